// Round 3
// baseline (402.035 us; speedup 1.0000x reference)
//
#include <hip/hip_runtime.h>
#include <cstdint>
#include <cstddef>

// ---------- types / helpers ----------
typedef __attribute__((ext_vector_type(8))) short bf16x8;           // 8 bf16 = 4 VGPR
typedef __attribute__((ext_vector_type(8))) unsigned short u16x8;   // raw 16B load
typedef __attribute__((ext_vector_type(4))) unsigned short u16x4;   // 8B store
typedef __attribute__((ext_vector_type(4))) float f32x4;            // MFMA C/D

#define MFMA16(A, B, C) __builtin_amdgcn_mfma_f32_16x16x32_bf16((A), (B), (C), 0, 0, 0)

__device__ __forceinline__ unsigned short f2bf(float f) {
  unsigned u = __builtin_bit_cast(unsigned, f);
  u += 0x7FFFu + ((u >> 16) & 1u);   // RNE
  return (unsigned short)(u >> 16);
}

// global -> LDS async, 16B/lane. LDS dest wave-uniform (HW adds lane*16).
__device__ __forceinline__ void gload_lds16(const void* gsrc, void* ldst) {
  __builtin_amdgcn_global_load_lds(
      (const __attribute__((address_space(1))) unsigned int*)gsrc,
      (__attribute__((address_space(3))) unsigned int*)ldst,
      16, 0, 0);
}

// ---------- f32 -> bf16 down-convert (memory-bound, ~25us total) ----------
__global__ __launch_bounds__(256) void cvt_bf16(const float* __restrict__ src,
                                                unsigned short* __restrict__ dst) {
  const int i = (blockIdx.x * 256 + threadIdx.x) * 4;   // n is multiple of 1024
  f32x4 v = *(const f32x4*)(src + i);
  u16x4 o;
  o[0] = f2bf(v[0]); o[1] = f2bf(v[1]); o[2] = f2bf(v[2]); o[3] = f2bf(v[3]);
  *(u16x4*)(dst + i) = o;
}

// ---------- GEMM: C[m][n] = sum_k A[m][k]*W[n][k] + bias[n]  (B^T layout) ----------
// m97 structure: 128x128 tile, BK=32, 4 waves (2x2), each wave 64x64 = 4x4 16x16 frags.
// MODE 0: C row-major [M][N] FLOAT32 (final output).
// MODE 1: QKV head-permute [bh][s][dk] bf16 (b=m>>11, h=n>>7).
template <int MODE>
__device__ __forceinline__ void gemm_tile(const unsigned short* __restrict__ A,
                                          const unsigned short* __restrict__ W,
                                          const float* __restrict__ bias,
                                          void* __restrict__ C,
                                          int bx, int by) {
  constexpr int K = 2048, N = 2048;
  __shared__ unsigned short lA[128 * 32];  // 8KB, linear [row][k]
  __shared__ unsigned short lB[128 * 32];  // 8KB
  const int tid = threadIdx.x;
  const int lane = tid & 63;
  const int w = tid >> 6;
  const int g = lane >> 4;
  const int l15 = lane & 15;
  const int wr = w >> 1, wc = w & 1;
  const int m0 = by * 128, n0 = bx * 128;

  f32x4 acc[4][4];
#pragma unroll
  for (int i = 0; i < 4; ++i)
#pragma unroll
    for (int j = 0; j < 4; ++j) acc[i][j] = f32x4{0.f, 0.f, 0.f, 0.f};

  for (int kt = 0; kt < K / 32; ++kt) {
    __syncthreads();  // prev iter's ds_reads done
    const int kb = kt * 32;
    // stage A,B: 128x32 bf16 = 512 16B-slots each; 2 iters x 256 thr
#pragma unroll
    for (int it = 0; it < 2; ++it) {
      const int f = it * 256 + tid;         // slot index
      const int r = f >> 2, s = f & 3;      // row, 16B-slot-in-row
      char* dA = (char*)lA + (it * 256 + w * 64) * 16;  // wave-uniform dest
      char* dB = (char*)lB + (it * 256 + w * 64) * 16;
      gload_lds16(A + (size_t)(m0 + r) * K + kb + s * 8, dA);
      gload_lds16(W + (size_t)(n0 + r) * K + kb + s * 8, dB);
    }
    __syncthreads();  // drains vmcnt (compiler emits waitcnt before barrier)
    bf16x8 af[4], bfr[4];
#pragma unroll
    for (int mi = 0; mi < 4; ++mi)
      af[mi] = *(const bf16x8*)&lA[(wr * 64 + mi * 16 + l15) * 32 + g * 8];
#pragma unroll
    for (int ni = 0; ni < 4; ++ni)
      bfr[ni] = *(const bf16x8*)&lB[(wc * 64 + ni * 16 + l15) * 32 + g * 8];
#pragma unroll
    for (int mi = 0; mi < 4; ++mi)
#pragma unroll
      for (int ni = 0; ni < 4; ++ni)
        acc[mi][ni] = MFMA16(af[mi], bfr[ni], acc[mi][ni]);
  }

  // epilogue: D layout col=lane&15, row=(lane>>4)*4+reg
#pragma unroll
  for (int ni = 0; ni < 4; ++ni) {
    const int n = n0 + wc * 64 + ni * 16 + l15;
    const float bval = bias[n];
#pragma unroll
    for (int mi = 0; mi < 4; ++mi) {
      const int mb = m0 + wr * 64 + mi * 16 + g * 4;
#pragma unroll
      for (int r = 0; r < 4; ++r) {
        const int m = mb + r;
        const float fv = acc[mi][ni][r] + bval;
        if (MODE == 0) {
          ((float*)C)[(size_t)m * N + n] = fv;               // f32 final output
        } else {
          const int bb = m >> 11, ss = m & 2047, hh = n >> 7, dk = n & 127;
          ((unsigned short*)C)[(((size_t)(bb * 16 + hh) * 2048) + ss) * 128 + dk] =
              f2bf(fv);
        }
      }
    }
  }
}

__global__ __launch_bounds__(256) void gemm_qkv(
    const unsigned short* __restrict__ x,
    const unsigned short* __restrict__ wq, const float* __restrict__ bq,
    const unsigned short* __restrict__ wk, const float* __restrict__ bk,
    const unsigned short* __restrict__ wv, const float* __restrict__ bv,
    unsigned short* __restrict__ qo, unsigned short* __restrict__ ko,
    unsigned short* __restrict__ vo) {
  const int z = blockIdx.z;
  const unsigned short* W = (z == 0) ? wq : (z == 1) ? wk : wv;
  const float* B = (z == 0) ? bq : (z == 1) ? bk : bv;
  unsigned short* O = (z == 0) ? qo : (z == 1) ? ko : vo;
  gemm_tile<1>(x, W, B, O, blockIdx.x, blockIdx.y);
}

__global__ __launch_bounds__(256) void gemm_out(
    const unsigned short* __restrict__ A, const unsigned short* __restrict__ wo,
    const float* __restrict__ bo, float* __restrict__ C) {
  gemm_tile<0>(A, wo, bo, C, blockIdx.x, blockIdx.y);
}

// ---------- causal flash attention ----------
// Q/K/V layout [bh=32][s=2048][dk=128] bf16. 4 waves x 16 q-rows (QBLK=64), KVBLK=64.
// K tile: global_load_lds linear dest + XOR-swizzled SOURCE; reads apply same XOR
// (rule #21: both-sides-or-neither). V: reg-staged, transposed into padded LDS.
__global__ __launch_bounds__(256) void attn_fwd(const unsigned short* __restrict__ Q,
                                                const unsigned short* __restrict__ K,
                                                const unsigned short* __restrict__ V,
                                                unsigned short* __restrict__ O) {
  __shared__ unsigned short lK[64 * 128];   // 16KB, swizzled rows (also Q prologue)
  __shared__ unsigned short lV[128 * 72];   // V^T [d][j], pad->144B rows (16B-aligned)
  __shared__ unsigned short lP[4][16 * 72]; // per-wave P tile [i][j], stride 144B
  const int tid = threadIdx.x;
  const int lane = tid & 63;
  const int w = tid >> 6;
  const int g = lane >> 4;
  const int l15 = lane & 15;
  const int qb = blockIdx.x;   // q block (64 rows)
  const int bh = blockIdx.y;   // b*16+h
  const size_t head_off = (size_t)bh * 2048 * 128;
  const unsigned short* Qh = Q + head_off;
  const unsigned short* Kh = K + head_off;
  const unsigned short* Vh = V + head_off;

  // ---- prologue: stage Q tile [64][128] (swizzled source), read A-frags to regs
#pragma unroll
  for (int it = 0; it < 4; ++it) {
    const int f = it * 256 + tid;          // 1024 slots
    const int r = f >> 4, s = f & 15;
    const int sc = s ^ (r & 7);            // inverse swizzle on SOURCE
    gload_lds16(Qh + (size_t)(qb * 64 + r) * 128 + sc * 8,
                (char*)lK + (it * 256 + w * 64) * 16);
  }
  __syncthreads();
  bf16x8 qf[4];
  {
    const int r = w * 16 + l15;            // wave's q-row
#pragma unroll
    for (int ks = 0; ks < 4; ++ks) {
      const int s = ks * 4 + g;
      qf[ks] = *(const bf16x8*)&lK[r * 128 + (s ^ (r & 7)) * 8];
    }
  }

  f32x4 acc_o[8];
#pragma unroll
  for (int i = 0; i < 8; ++i) acc_o[i] = f32x4{0.f, 0.f, 0.f, 0.f};
  float mrun[4], lrun[4];
#pragma unroll
  for (int r = 0; r < 4; ++r) { mrun[r] = -__builtin_inff(); lrun[r] = 0.0f; }

  const float SL2E = 0.12751744f;          // (1/sqrt(128)) * log2(e)
  const int irow_base = qb * 64 + w * 16 + g * 4;  // + reg r = global q row

  for (int kv = 0; kv <= qb; ++kv) {
    const int kv0 = kv * 64;
    __syncthreads();  // everyone done reading lK/lV from prev iter
    // stage K tile (swizzled source, linear dest)
#pragma unroll
    for (int it = 0; it < 4; ++it) {
      const int f = it * 256 + tid;
      const int r = f >> 4, s = f & 15;
      const int sc = s ^ (r & 7);
      gload_lds16(Kh + (size_t)(kv0 + r) * 128 + sc * 8,
                  (char*)lK + (it * 256 + w * 64) * 16);
    }
    // stage V transposed: thread covers j0..j0+1 x d0..d0+15, packs pairs -> b32
    {
      const int j0 = (tid & 31) * 2;
      const int d0 = (tid >> 5) * 16;
      const unsigned short* vp = Vh + (size_t)(kv0 + j0) * 128 + d0;
      u16x8 va0 = *(const u16x8*)(vp);
      u16x8 va1 = *(const u16x8*)(vp + 8);
      u16x8 vb0 = *(const u16x8*)(vp + 128);
      u16x8 vb1 = *(const u16x8*)(vp + 136);
#pragma unroll
      for (int dd = 0; dd < 8; ++dd) {
        unsigned pk0 = (unsigned)va0[dd] | ((unsigned)vb0[dd] << 16);
        unsigned pk1 = (unsigned)va1[dd] | ((unsigned)vb1[dd] << 16);
        *(unsigned*)&lV[(d0 + dd) * 72 + j0] = pk0;
        *(unsigned*)&lV[(d0 + 8 + dd) * 72 + j0] = pk1;
      }
    }
    __syncthreads();

    // ---- QK^T: S[i][j], wave owns 16 i-rows x 64 j
    f32x4 sacc[4];
#pragma unroll
    for (int jb = 0; jb < 4; ++jb) sacc[jb] = f32x4{0.f, 0.f, 0.f, 0.f};
#pragma unroll
    for (int jb = 0; jb < 4; ++jb) {
      const int r = jb * 16 + l15;
#pragma unroll
      for (int ks = 0; ks < 4; ++ks) {
        const int s = ks * 4 + g;
        bf16x8 kf = *(const bf16x8*)&lK[r * 128 + (s ^ (r & 7)) * 8];
        sacc[jb] = MFMA16(qf[ks], kf, sacc[jb]);
      }
    }

    // ---- scale + causal mask (log2 domain)
    const bool diag = (kv == qb);
    float p[4][4];
#pragma unroll
    for (int jb = 0; jb < 4; ++jb) {
      const int j = kv0 + jb * 16 + l15;
#pragma unroll
      for (int r = 0; r < 4; ++r) {
        float t = sacc[jb][r] * SL2E;
        if (diag && j > irow_base + r) t = -__builtin_inff();
        p[jb][r] = t;
      }
    }

    // ---- online softmax; rows live per quarter-wave -> 16-lane xor butterflies
    float psc[4];
#pragma unroll
    for (int r = 0; r < 4; ++r) {
      float mx = fmaxf(fmaxf(p[0][r], p[1][r]), fmaxf(p[2][r], p[3][r]));
      mx = fmaxf(mx, __shfl_xor(mx, 1));
      mx = fmaxf(mx, __shfl_xor(mx, 2));
      mx = fmaxf(mx, __shfl_xor(mx, 4));
      mx = fmaxf(mx, __shfl_xor(mx, 8));
      const float mnew = fmaxf(mrun[r], mx);
      const float sc = exp2f(mrun[r] - mnew);   // 0 on first tile (-inf)
      mrun[r] = mnew;
      float rs = 0.f;
#pragma unroll
      for (int jb = 0; jb < 4; ++jb) {
        const float e = exp2f(p[jb][r] - mnew);
        p[jb][r] = e;
        rs += e;
      }
      rs += __shfl_xor(rs, 1);
      rs += __shfl_xor(rs, 2);
      rs += __shfl_xor(rs, 4);
      rs += __shfl_xor(rs, 8);
      lrun[r] = lrun[r] * sc + rs;
      psc[r] = sc;
    }
#pragma unroll
    for (int nb = 0; nb < 8; ++nb)
#pragma unroll
      for (int r = 0; r < 4; ++r) acc_o[nb][r] *= psc[r];

    // ---- P -> per-wave LDS (bf16), re-fragment as MFMA A operand
#pragma unroll
    for (int jb = 0; jb < 4; ++jb)
#pragma unroll
      for (int r = 0; r < 4; ++r)
        lP[w][(g * 4 + r) * 72 + jb * 16 + l15] = f2bf(p[jb][r]);
    bf16x8 pa[2];
#pragma unroll
    for (int ks2 = 0; ks2 < 2; ++ks2)
      pa[ks2] = *(const bf16x8*)&lP[w][l15 * 72 + ks2 * 32 + g * 8];

    // ---- PV: acc_o[i][d] += P[i][j] * V[j][d]; B^T rows = V^T[d][j] from lV
#pragma unroll
    for (int nb = 0; nb < 8; ++nb) {
      const int vrow = nb * 16 + l15;
#pragma unroll
      for (int ks2 = 0; ks2 < 2; ++ks2) {
        bf16x8 vf = *(const bf16x8*)&lV[vrow * 72 + ks2 * 32 + g * 8];
        acc_o[nb] = MFMA16(pa[ks2], vf, acc_o[nb]);
      }
    }
  }

  // ---- epilogue: O[b][i][h*128+d] bf16 (internal buffer)
  const int b = bh >> 4, h = bh & 15;
#pragma unroll
  for (int nb = 0; nb < 8; ++nb) {
#pragma unroll
    for (int r = 0; r < 4; ++r) {
      const int i = qb * 64 + w * 16 + g * 4 + r;
      const float o = acc_o[nb][r] / lrun[r];
      O[((size_t)(b * 2048 + i)) * 2048 + h * 128 + nb * 16 + l15] = f2bf(o);
    }
  }
}

// ---------- launch ----------
extern "C" void kernel_launch(void* const* d_in, const int* in_sizes, int n_in,
                              void* d_out, int out_size, void* d_ws, size_t ws_size,
                              hipStream_t stream) {
  // Inputs FLOAT32; final output FLOAT32 (reference output dtype). Internal bf16.
  const float* x  = (const float*)d_in[0];
  const float* wq = (const float*)d_in[1];
  const float* bq = (const float*)d_in[2];
  const float* wk = (const float*)d_in[3];
  const float* bk = (const float*)d_in[4];
  const float* wv = (const float*)d_in[5];
  const float* bv = (const float*)d_in[6];
  const float* wo = (const float*)d_in[7];
  const float* bo = (const float*)d_in[8];
  // d_in[9] = mask (int32 tril) — causality hardcoded in attn_fwd.

  const size_t NX = (size_t)2 * 2048 * 2048;   // x / per-QKV-buffer elems (8.39M)
  const size_t NW = (size_t)2048 * 2048;       // weight elems (4.19M)
  // ws layout (bf16 elems): xbf | wq | wk | wv | wo | q | k | v ; ao aliases xbf
  const size_t need = (NX + 4 * NW + 3 * NX) * sizeof(unsigned short);  // 96 MB
  if (ws_size < need) return;
  unsigned short* xbf  = (unsigned short*)d_ws;
  unsigned short* wqb  = xbf + NX;
  unsigned short* wkb  = wqb + NW;
  unsigned short* wvb  = wkb + NW;
  unsigned short* wob  = wvb + NW;
  unsigned short* qbuf = wob + NW;
  unsigned short* kbuf = qbuf + NX;
  unsigned short* vbuf = kbuf + NX;
  unsigned short* aobuf = xbf;  // x dead after gemm_qkv (stream-ordered)

  // f32 -> bf16 converts (grid-exact: sizes are multiples of 1024)
  cvt_bf16<<<NX / 1024, 256, 0, stream>>>(x, xbf);
  cvt_bf16<<<NW / 1024, 256, 0, stream>>>(wq, wqb);
  cvt_bf16<<<NW / 1024, 256, 0, stream>>>(wk, wkb);
  cvt_bf16<<<NW / 1024, 256, 0, stream>>>(wv, wvb);
  cvt_bf16<<<NW / 1024, 256, 0, stream>>>(wo, wob);

  // QKV projections (fused launch, z selects weight/bias/dst), head-permuted output
  gemm_qkv<<<dim3(16, 32, 3), 256, 0, stream>>>(xbf, wqb, bq, wkb, bk, wvb, bv,
                                                qbuf, kbuf, vbuf);
  // causal flash attention -> [b][s][h*dk] bf16 (row-major for O-proj)
  attn_fwd<<<dim3(32, 32), 256, 0, stream>>>(qbuf, kbuf, vbuf, aobuf);
  // output projection -> d_out (float32)
  gemm_out<<<dim3(16, 32), 256, 0, stream>>>(aobuf, wob, bo, (float*)d_out);
}

// Round 4
// 344.241 us; speedup vs baseline: 1.1679x; 1.1679x over previous
//
#include <hip/hip_runtime.h>
#include <cstdint>
#include <cstddef>

// ---------- types / helpers ----------
typedef __attribute__((ext_vector_type(8))) short bf16x8;           // 8 bf16 = 4 VGPR
typedef __attribute__((ext_vector_type(8))) unsigned short u16x8;   // raw 16B load
typedef __attribute__((ext_vector_type(4))) unsigned short u16x4;   // 8B store
typedef __attribute__((ext_vector_type(4))) float f32x4;            // MFMA C/D

#define MFMA16(A, B, C) __builtin_amdgcn_mfma_f32_16x16x32_bf16((A), (B), (C), 0, 0, 0)

__device__ __forceinline__ unsigned short f2bf(float f) {
  unsigned u = __builtin_bit_cast(unsigned, f);
  u += 0x7FFFu + ((u >> 16) & 1u);   // RNE
  return (unsigned short)(u >> 16);
}

// global -> LDS async, 16B/lane. LDS dest wave-uniform (HW adds lane*16).
__device__ __forceinline__ void gload_lds16(const void* gsrc, void* ldst) {
  __builtin_amdgcn_global_load_lds(
      (const __attribute__((address_space(1))) unsigned int*)gsrc,
      (__attribute__((address_space(3))) unsigned int*)ldst,
      16, 0, 0);
}

// ---------- fused f32 -> bf16 down-convert (1 launch for x + 4 weights) ----------
// grid (4096, 6): y=0,1 -> x halves (4M elems each); y=2..5 -> weights (4M each)
__global__ __launch_bounds__(256) void cvt_all(
    const float* __restrict__ sx, const float* __restrict__ s1,
    const float* __restrict__ s2, const float* __restrict__ s3,
    const float* __restrict__ s4,
    unsigned short* __restrict__ dx, unsigned short* __restrict__ d1,
    unsigned short* __restrict__ d2, unsigned short* __restrict__ d3,
    unsigned short* __restrict__ d4) {
  const int y = blockIdx.y;
  const float* src;
  unsigned short* dst;
  if (y == 0)      { src = sx;               dst = dx; }
  else if (y == 1) { src = sx + (1u << 22);  dst = dx + (1u << 22); }
  else if (y == 2) { src = s1; dst = d1; }
  else if (y == 3) { src = s2; dst = d2; }
  else if (y == 4) { src = s3; dst = d3; }
  else             { src = s4; dst = d4; }
  const size_t i = ((size_t)blockIdx.x * 256 + threadIdx.x) * 4;
  f32x4 v = *(const f32x4*)(src + i);
  u16x4 o;
  o[0] = f2bf(v[0]); o[1] = f2bf(v[1]); o[2] = f2bf(v[2]); o[3] = f2bf(v[3]);
  *(u16x4*)(dst + i) = o;
}

// ---------- GEMM: C[m][n] = sum_k A[m][k]*W[n][k] + bias[n]  (B^T layout) ----------
// m97 structure: 128x128 tile, BK=32, 4 waves (2x2), each wave 64x64 = 4x4 16x16 frags.
// MODE 0: C row-major [M][N] FLOAT32 (final output).
// MODE 1: QKV head-permute [bh][s][dk] bf16 (b=m>>11, h=n>>7).
template <int MODE>
__device__ __forceinline__ void gemm_tile(const unsigned short* __restrict__ A,
                                          const unsigned short* __restrict__ W,
                                          const float* __restrict__ bias,
                                          void* __restrict__ C,
                                          int bx, int by) {
  constexpr int K = 2048, N = 2048;
  __shared__ unsigned short lA[128 * 32];  // 8KB, linear [row][k]
  __shared__ unsigned short lB[128 * 32];  // 8KB
  const int tid = threadIdx.x;
  const int lane = tid & 63;
  const int w = tid >> 6;
  const int g = lane >> 4;
  const int l15 = lane & 15;
  const int wr = w >> 1, wc = w & 1;
  const int m0 = by * 128, n0 = bx * 128;

  f32x4 acc[4][4];
#pragma unroll
  for (int i = 0; i < 4; ++i)
#pragma unroll
    for (int j = 0; j < 4; ++j) acc[i][j] = f32x4{0.f, 0.f, 0.f, 0.f};

  for (int kt = 0; kt < K / 32; ++kt) {
    __syncthreads();
    const int kb = kt * 32;
#pragma unroll
    for (int it = 0; it < 2; ++it) {
      const int f = it * 256 + tid;
      const int r = f >> 2, s = f & 3;
      char* dA = (char*)lA + (it * 256 + w * 64) * 16;
      char* dB = (char*)lB + (it * 256 + w * 64) * 16;
      gload_lds16(A + (size_t)(m0 + r) * K + kb + s * 8, dA);
      gload_lds16(W + (size_t)(n0 + r) * K + kb + s * 8, dB);
    }
    __syncthreads();
    bf16x8 af[4], bfr[4];
#pragma unroll
    for (int mi = 0; mi < 4; ++mi)
      af[mi] = *(const bf16x8*)&lA[(wr * 64 + mi * 16 + l15) * 32 + g * 8];
#pragma unroll
    for (int ni = 0; ni < 4; ++ni)
      bfr[ni] = *(const bf16x8*)&lB[(wc * 64 + ni * 16 + l15) * 32 + g * 8];
#pragma unroll
    for (int mi = 0; mi < 4; ++mi)
#pragma unroll
      for (int ni = 0; ni < 4; ++ni)
        acc[mi][ni] = MFMA16(af[mi], bfr[ni], acc[mi][ni]);
  }

  // epilogue: D layout col=lane&15, row=(lane>>4)*4+reg
#pragma unroll
  for (int ni = 0; ni < 4; ++ni) {
    const int n = n0 + wc * 64 + ni * 16 + l15;
    const float bval = bias[n];
#pragma unroll
    for (int mi = 0; mi < 4; ++mi) {
      const int mb = m0 + wr * 64 + mi * 16 + g * 4;
#pragma unroll
      for (int r = 0; r < 4; ++r) {
        const int m = mb + r;
        const float fv = acc[mi][ni][r] + bval;
        if (MODE == 0) {
          ((float*)C)[(size_t)m * N + n] = fv;               // f32 final output
        } else {
          const int bb = m >> 11, ss = m & 2047, hh = n >> 7, dk = n & 127;
          ((unsigned short*)C)[(((size_t)(bb * 16 + hh) * 2048) + ss) * 128 + dk] =
              f2bf(fv);
        }
      }
    }
  }
}

__global__ __launch_bounds__(256) void gemm_qkv(
    const unsigned short* __restrict__ x,
    const unsigned short* __restrict__ wq, const float* __restrict__ bq,
    const unsigned short* __restrict__ wk, const float* __restrict__ bk,
    const unsigned short* __restrict__ wv, const float* __restrict__ bv,
    unsigned short* __restrict__ qo, unsigned short* __restrict__ ko,
    unsigned short* __restrict__ vo) {
  const int z = blockIdx.z;
  const unsigned short* W = (z == 0) ? wq : (z == 1) ? wk : wv;
  const float* B = (z == 0) ? bq : (z == 1) ? bk : bv;
  unsigned short* O = (z == 0) ? qo : (z == 1) ? ko : vo;
  gemm_tile<1>(x, W, B, O, blockIdx.x, blockIdx.y);
}

__global__ __launch_bounds__(256) void gemm_out(
    const unsigned short* __restrict__ A, const unsigned short* __restrict__ wo,
    const float* __restrict__ bo, float* __restrict__ C) {
  gemm_tile<0>(A, wo, bo, C, blockIdx.x, blockIdx.y);
}

// ---------- causal flash attention, pipelined ----------
// Q/K/V [bh=32][s=2048][dk=128] bf16. QBLK=128 (4 waves x 32 q-rows), KVBLK=64.
// K: double-buffered global_load_lds, XOR-swizzled source + swizzled reads (rule #21).
// V: global->reg issued at iter start, LDS-write after barrier (T14 split).
// Each K/V fragment feeds 2 MFMAs (2 q-frags/wave) -> 2:1 MFMA:ds_read.
__global__ __launch_bounds__(256, 2) void attn_fwd(
    const unsigned short* __restrict__ Q, const unsigned short* __restrict__ K,
    const unsigned short* __restrict__ V, unsigned short* __restrict__ O) {
  __shared__ unsigned short lK[2][64 * 128];  // 2x16KB dbuf (swizzled slots)
  __shared__ unsigned short lV[128 * 72];     // V^T [d][j], stride 72 (144B rows)
  __shared__ unsigned short lP[4][32 * 72];   // per-wave P [row][j], stride 72
  const int tid = threadIdx.x;
  const int lane = tid & 63;
  const int w = tid >> 6;
  const int g = lane >> 4;
  const int l15 = lane & 15;
  const int qb = 15 - (int)blockIdx.x;        // longest-first dispatch
  const int bh = blockIdx.y;
  const int nt = 2 * qb + 2;                  // kv tiles (64-wide) in causal span
  const size_t head_off = (size_t)bh * 2048 * 128;
  const unsigned short* Qh = Q + head_off;
  const unsigned short* Kh = K + head_off;
  const unsigned short* Vh = V + head_off;

  // ---- Q fragments: direct global->reg (rows exclusive to this block; 64B chunks)
  bf16x8 qf[2][4];
#pragma unroll
  for (int mi = 0; mi < 2; ++mi) {
    const int row = qb * 128 + w * 32 + mi * 16 + l15;
#pragma unroll
    for (int ks = 0; ks < 4; ++ks) {
      const int s = ks * 4 + g;
      qf[mi][ks] = *(const bf16x8*)(Qh + (size_t)row * 128 + s * 8);
    }
  }

  const int vj0 = (tid & 31) * 2;   // V-staging: 2 j x 16 d per thread
  const int vd0 = (tid >> 5) * 16;
  u16x8 vr[4];

  auto stageK = [&](int t, int buf) {
#pragma unroll
    for (int it = 0; it < 4; ++it) {
      const int f = it * 256 + tid;
      const int r = f >> 4, s = f & 15;
      const int sc = s ^ (r & 7);             // inverse swizzle on SOURCE
      gload_lds16(Kh + (size_t)(t * 64 + r) * 128 + sc * 8,
                  (char*)&lK[buf][0] + (it * 256 + w * 64) * 16);
    }
  };
  auto loadV = [&](int t) {
    const unsigned short* vp = Vh + (size_t)(t * 64 + vj0) * 128 + vd0;
    vr[0] = *(const u16x8*)(vp);
    vr[1] = *(const u16x8*)(vp + 8);
    vr[2] = *(const u16x8*)(vp + 128);
    vr[3] = *(const u16x8*)(vp + 136);
  };
  auto writeV = [&]() {                       // compiler inserts vmcnt wait on vr
#pragma unroll
    for (int dd = 0; dd < 8; ++dd) {
      unsigned pk0 = (unsigned)vr[0][dd] | ((unsigned)vr[2][dd] << 16);
      unsigned pk1 = (unsigned)vr[1][dd] | ((unsigned)vr[3][dd] << 16);
      *(unsigned*)&lV[(vd0 + dd) * 72 + vj0] = pk0;
      *(unsigned*)&lV[(vd0 + 8 + dd) * 72 + vj0] = pk1;
    }
  };

  // ---- prologue: K(0) -> lK[0], V(0) -> lV
  stageK(0, 0);
  loadV(0);
  writeV();
  __syncthreads();

  f32x4 acc_o[2][8];
#pragma unroll
  for (int mi = 0; mi < 2; ++mi)
#pragma unroll
    for (int i = 0; i < 8; ++i) acc_o[mi][i] = f32x4{0.f, 0.f, 0.f, 0.f};
  float mrun[2][4], lrun[2][4];
#pragma unroll
  for (int mi = 0; mi < 2; ++mi)
#pragma unroll
    for (int r = 0; r < 4; ++r) { mrun[mi][r] = -__builtin_inff(); lrun[mi][r] = 0.f; }

  const float SL2E = 0.12751744f;             // (1/sqrt(128)) * log2(e)
  const int wrow_min = qb * 128 + w * 32;     // wave's first q-row

  int cur = 0;
  for (int t = 0; t < nt; ++t) {
    const int kv0 = t * 64;
    const bool pre = (t + 1 < nt);
    if (pre) { stageK(t + 1, cur ^ 1); loadV(t + 1); }   // prefetch under compute

    const bool active = (kv0 <= wrow_min + 31);  // wave-uniform: skip fully-masked
    if (active) {
      const unsigned short* lKc = &lK[cur][0];
      // ---- QK^T: each kf feeds both q-frags
      f32x4 sacc[2][4];
#pragma unroll
      for (int mi = 0; mi < 2; ++mi)
#pragma unroll
        for (int jb = 0; jb < 4; ++jb) sacc[mi][jb] = f32x4{0.f, 0.f, 0.f, 0.f};
#pragma unroll
      for (int jb = 0; jb < 4; ++jb) {
        const int r = jb * 16 + l15;
#pragma unroll
        for (int ks = 0; ks < 4; ++ks) {
          const int s = ks * 4 + g;
          bf16x8 kf = *(const bf16x8*)&lKc[r * 128 + (s ^ (r & 7)) * 8];
          sacc[0][jb] = MFMA16(qf[0][ks], kf, sacc[0][jb]);
          sacc[1][jb] = MFMA16(qf[1][ks], kf, sacc[1][jb]);
        }
      }

      const bool need_mask = (kv0 + 63 > wrow_min);
#pragma unroll
      for (int mi = 0; mi < 2; ++mi) {
        // ---- scale + causal mask (log2 domain)
        float p[4][4];
#pragma unroll
        for (int jb = 0; jb < 4; ++jb) {
          const int j = kv0 + jb * 16 + l15;
#pragma unroll
          for (int r = 0; r < 4; ++r) {
            float tv = sacc[mi][jb][r] * SL2E;
            if (need_mask && j > wrow_min + mi * 16 + g * 4 + r)
              tv = -__builtin_inff();
            p[jb][r] = tv;
          }
        }
        // ---- online softmax (rows per quarter-wave, 16-lane butterflies)
        float psc[4];
#pragma unroll
        for (int r = 0; r < 4; ++r) {
          float mx = fmaxf(fmaxf(p[0][r], p[1][r]), fmaxf(p[2][r], p[3][r]));
          mx = fmaxf(mx, __shfl_xor(mx, 1));
          mx = fmaxf(mx, __shfl_xor(mx, 2));
          mx = fmaxf(mx, __shfl_xor(mx, 4));
          mx = fmaxf(mx, __shfl_xor(mx, 8));
          const float mnew = fmaxf(mrun[mi][r], mx);
          const float sc = exp2f(mrun[mi][r] - mnew);
          mrun[mi][r] = mnew;
          float rs = 0.f;
#pragma unroll
          for (int jb = 0; jb < 4; ++jb) {
            const float e = exp2f(p[jb][r] - mnew);
            p[jb][r] = e;
            rs += e;
          }
          rs += __shfl_xor(rs, 1);
          rs += __shfl_xor(rs, 2);
          rs += __shfl_xor(rs, 4);
          rs += __shfl_xor(rs, 8);
          lrun[mi][r] = lrun[mi][r] * sc + rs;
          psc[r] = sc;
        }
#pragma unroll
        for (int nb = 0; nb < 8; ++nb)
#pragma unroll
          for (int r = 0; r < 4; ++r) acc_o[mi][nb][r] *= psc[r];
        // ---- P -> per-wave LDS
#pragma unroll
        for (int jb = 0; jb < 4; ++jb)
#pragma unroll
          for (int r = 0; r < 4; ++r)
            lP[w][(mi * 16 + g * 4 + r) * 72 + jb * 16 + l15] = f2bf(p[jb][r]);
      }

      // ---- PV: each vf feeds both P-frags
      bf16x8 pa[2][2];
#pragma unroll
      for (int mi = 0; mi < 2; ++mi)
#pragma unroll
        for (int ks2 = 0; ks2 < 2; ++ks2)
          pa[mi][ks2] =
              *(const bf16x8*)&lP[w][(mi * 16 + l15) * 72 + ks2 * 32 + g * 8];
#pragma unroll
      for (int nb = 0; nb < 8; ++nb) {
        const int vrow = nb * 16 + l15;
#pragma unroll
        for (int ks2 = 0; ks2 < 2; ++ks2) {
          bf16x8 vf = *(const bf16x8*)&lV[vrow * 72 + ks2 * 32 + g * 8];
          acc_o[0][nb] = MFMA16(pa[0][ks2], vf, acc_o[0][nb]);
          acc_o[1][nb] = MFMA16(pa[1][ks2], vf, acc_o[1][nb]);
        }
      }
    }

    __syncthreads();          // all waves done reading lV(t), lK[cur]
    if (pre) writeV();        // V^T(t+1) -> lV (vmcnt wait auto-inserted)
    __syncthreads();          // lV(t+1) + lK[cur^1] ready
    cur ^= 1;
  }

  // ---- epilogue: O[b][i][h*128+d] bf16
  const int b = bh >> 4, h = bh & 15;
#pragma unroll
  for (int mi = 0; mi < 2; ++mi)
#pragma unroll
    for (int nb = 0; nb < 8; ++nb)
#pragma unroll
      for (int r = 0; r < 4; ++r) {
        const int i = qb * 128 + w * 32 + mi * 16 + g * 4 + r;
        const float o = acc_o[mi][nb][r] / lrun[mi][r];
        O[((size_t)(b * 2048 + i)) * 2048 + h * 128 + nb * 16 + l15] = f2bf(o);
      }
}

// ---------- launch ----------
extern "C" void kernel_launch(void* const* d_in, const int* in_sizes, int n_in,
                              void* d_out, int out_size, void* d_ws, size_t ws_size,
                              hipStream_t stream) {
  // Inputs FLOAT32; final output FLOAT32. Internal compute bf16.
  const float* x  = (const float*)d_in[0];
  const float* wq = (const float*)d_in[1];
  const float* bq = (const float*)d_in[2];
  const float* wk = (const float*)d_in[3];
  const float* bk = (const float*)d_in[4];
  const float* wv = (const float*)d_in[5];
  const float* bv = (const float*)d_in[6];
  const float* wo = (const float*)d_in[7];
  const float* bo = (const float*)d_in[8];
  // d_in[9] = mask (int32 tril) — causality hardcoded in attn_fwd.

  const size_t NX = (size_t)2 * 2048 * 2048;   // 8.39M elems
  const size_t NW = (size_t)2048 * 2048;       // 4.19M elems
  const size_t need = (NX + 4 * NW + 3 * NX) * sizeof(unsigned short);  // 96 MB
  if (ws_size < need) return;
  unsigned short* xbf  = (unsigned short*)d_ws;
  unsigned short* wqb  = xbf + NX;
  unsigned short* wkb  = wqb + NW;
  unsigned short* wvb  = wkb + NW;
  unsigned short* wob  = wvb + NW;
  unsigned short* qbuf = wob + NW;
  unsigned short* kbuf = qbuf + NX;
  unsigned short* vbuf = kbuf + NX;
  unsigned short* aobuf = xbf;  // x dead after gemm_qkv (stream-ordered)

  // fused f32 -> bf16 converts (x + 4 weights, one launch)
  cvt_all<<<dim3(4096, 6), 256, 0, stream>>>(x, wq, wk, wv, wo,
                                             xbf, wqb, wkb, wvb, wob);

  // QKV projections (z selects weight/bias/dst), head-permuted bf16 output
  gemm_qkv<<<dim3(16, 32, 3), 256, 0, stream>>>(xbf, wqb, bq, wkb, bk, wvb, bv,
                                                qbuf, kbuf, vbuf);
  // causal flash attention -> [b][s][h*dk] bf16
  attn_fwd<<<dim3(16, 32), 256, 0, stream>>>(qbuf, kbuf, vbuf, aobuf);
  // output projection -> d_out (float32)
  gemm_out<<<dim3(16, 32), 256, 0, stream>>>(aobuf, wob, bo, (float*)d_out);
}

// Round 6
// 298.663 us; speedup vs baseline: 1.3461x; 1.1526x over previous
//
#include <hip/hip_runtime.h>
#include <cstdint>
#include <cstddef>

// ---------- types / helpers ----------
typedef __attribute__((ext_vector_type(8))) short bf16x8;           // 8 bf16 = 4 VGPR
typedef __attribute__((ext_vector_type(8))) unsigned short u16x8;   // raw 16B load
typedef __attribute__((ext_vector_type(4))) unsigned short u16x4;   // 8B store
typedef __attribute__((ext_vector_type(4))) float f32x4;            // MFMA C/D

#define MFMA16(A, B, C) __builtin_amdgcn_mfma_f32_16x16x32_bf16((A), (B), (C), 0, 0, 0)

__device__ __forceinline__ unsigned short f2bf(float f) {
  unsigned u = __builtin_bit_cast(unsigned, f);
  u += 0x7FFFu + ((u >> 16) & 1u);   // RNE
  return (unsigned short)(u >> 16);
}

// global -> LDS async, 16B/lane. LDS dest wave-uniform (HW adds lane*16).
__device__ __forceinline__ void gload_lds16(const void* gsrc, void* ldst) {
  __builtin_amdgcn_global_load_lds(
      (const __attribute__((address_space(1))) unsigned int*)gsrc,
      (__attribute__((address_space(3))) unsigned int*)ldst,
      16, 0, 0);
}

// ---------- fused f32 -> bf16 down-convert (1 launch for x + 4 weights) ----------
__global__ __launch_bounds__(256) void cvt_all(
    const float* __restrict__ sx, const float* __restrict__ s1,
    const float* __restrict__ s2, const float* __restrict__ s3,
    const float* __restrict__ s4,
    unsigned short* __restrict__ dx, unsigned short* __restrict__ d1,
    unsigned short* __restrict__ d2, unsigned short* __restrict__ d3,
    unsigned short* __restrict__ d4) {
  const int y = blockIdx.y;
  const float* src;
  unsigned short* dst;
  if (y == 0)      { src = sx;               dst = dx; }
  else if (y == 1) { src = sx + (1u << 22);  dst = dx + (1u << 22); }
  else if (y == 2) { src = s1; dst = d1; }
  else if (y == 3) { src = s2; dst = d2; }
  else if (y == 4) { src = s3; dst = d3; }
  else             { src = s4; dst = d4; }
  const size_t i = ((size_t)blockIdx.x * 256 + threadIdx.x) * 4;
  f32x4 v = *(const f32x4*)(src + i);
  u16x4 o;
  o[0] = f2bf(v[0]); o[1] = f2bf(v[1]); o[2] = f2bf(v[2]); o[3] = f2bf(v[3]);
  *(u16x4*)(dst + i) = o;
}

// ---------- GEMM (m97 structure, unchanged) ----------
template <int MODE>
__device__ __forceinline__ void gemm_tile(const unsigned short* __restrict__ A,
                                          const unsigned short* __restrict__ W,
                                          const float* __restrict__ bias,
                                          void* __restrict__ C,
                                          int bx, int by) {
  constexpr int K = 2048, N = 2048;
  __shared__ unsigned short lA[128 * 32];
  __shared__ unsigned short lB[128 * 32];
  const int tid = threadIdx.x;
  const int lane = tid & 63;
  const int w = tid >> 6;
  const int g = lane >> 4;
  const int l15 = lane & 15;
  const int wr = w >> 1, wc = w & 1;
  const int m0 = by * 128, n0 = bx * 128;

  f32x4 acc[4][4];
#pragma unroll
  for (int i = 0; i < 4; ++i)
#pragma unroll
    for (int j = 0; j < 4; ++j) acc[i][j] = f32x4{0.f, 0.f, 0.f, 0.f};

  for (int kt = 0; kt < K / 32; ++kt) {
    __syncthreads();
    const int kb = kt * 32;
#pragma unroll
    for (int it = 0; it < 2; ++it) {
      const int f = it * 256 + tid;
      const int r = f >> 2, s = f & 3;
      char* dA = (char*)lA + (it * 256 + w * 64) * 16;
      char* dB = (char*)lB + (it * 256 + w * 64) * 16;
      gload_lds16(A + (size_t)(m0 + r) * K + kb + s * 8, dA);
      gload_lds16(W + (size_t)(n0 + r) * K + kb + s * 8, dB);
    }
    __syncthreads();
    bf16x8 af[4], bfr[4];
#pragma unroll
    for (int mi = 0; mi < 4; ++mi)
      af[mi] = *(const bf16x8*)&lA[(wr * 64 + mi * 16 + l15) * 32 + g * 8];
#pragma unroll
    for (int ni = 0; ni < 4; ++ni)
      bfr[ni] = *(const bf16x8*)&lB[(wc * 64 + ni * 16 + l15) * 32 + g * 8];
#pragma unroll
    for (int mi = 0; mi < 4; ++mi)
#pragma unroll
      for (int ni = 0; ni < 4; ++ni)
        acc[mi][ni] = MFMA16(af[mi], bfr[ni], acc[mi][ni]);
  }

#pragma unroll
  for (int ni = 0; ni < 4; ++ni) {
    const int n = n0 + wc * 64 + ni * 16 + l15;
    const float bval = bias[n];
#pragma unroll
    for (int mi = 0; mi < 4; ++mi) {
      const int mb = m0 + wr * 64 + mi * 16 + g * 4;
#pragma unroll
      for (int r = 0; r < 4; ++r) {
        const int m = mb + r;
        const float fv = acc[mi][ni][r] + bval;
        if (MODE == 0) {
          ((float*)C)[(size_t)m * N + n] = fv;
        } else {
          const int bb = m >> 11, ss = m & 2047, hh = n >> 7, dk = n & 127;
          ((unsigned short*)C)[(((size_t)(bb * 16 + hh) * 2048) + ss) * 128 + dk] =
              f2bf(fv);
        }
      }
    }
  }
}

__global__ __launch_bounds__(256) void gemm_qkv(
    const unsigned short* __restrict__ x,
    const unsigned short* __restrict__ wq, const float* __restrict__ bq,
    const unsigned short* __restrict__ wk, const float* __restrict__ bk,
    const unsigned short* __restrict__ wv, const float* __restrict__ bv,
    unsigned short* __restrict__ qo, unsigned short* __restrict__ ko,
    unsigned short* __restrict__ vo) {
  const int z = blockIdx.z;
  const unsigned short* W = (z == 0) ? wq : (z == 1) ? wk : wv;
  const float* B = (z == 0) ? bq : (z == 1) ? bk : bv;
  unsigned short* O = (z == 0) ? qo : (z == 1) ? ko : vo;
  gemm_tile<1>(x, W, B, O, blockIdx.x, blockIdx.y);
}

__global__ __launch_bounds__(256) void gemm_out(
    const unsigned short* __restrict__ A, const unsigned short* __restrict__ wo,
    const float* __restrict__ bo, float* __restrict__ C) {
  gemm_tile<0>(A, wo, bo, C, blockIdx.x, blockIdx.y);
}

// ---------- causal flash attention, swapped-QK^T in-lane softmax ----------
// Swapped QK^T: sacc = mfma(K,Q) -> S^T; lane(g,l15) reg rr holds
// S[j=kv0+16jb+4g+rr][i=qrow0+16mi+l15]. Softmax over j = in-lane reduce over
// 16 regs + 2 shfl_xor (16,32); stats g-uniform. P -> per-wave LDS via scalar
// u16 stores (r4-proven store->bf16x8-read pattern) + sched_barrier(0) fence
// before the pa reads (forbids compile-time hoist of ds_read over ds_write).
__global__ __launch_bounds__(256, 2) void attn_fwd(
    const unsigned short* __restrict__ Q, const unsigned short* __restrict__ K,
    const unsigned short* __restrict__ V, unsigned short* __restrict__ O) {
  __shared__ unsigned short lK[2][64 * 128];  // 32KB dbuf (swizzled slots)
  __shared__ unsigned short lV[128 * 72];     // V^T [d][j], 144B rows
  __shared__ unsigned short lP[4][32 * 72];   // per-wave P [i][j], 144B rows
  const int tid = threadIdx.x;
  const int lane = tid & 63;
  const int w = tid >> 6;
  const int g = lane >> 4;
  const int l15 = lane & 15;
  // CU-pair balance: linear id c and c+256 share a CU (same bx; bh and bh+16);
  // complementary qb makes every CU's pair sum to 36 kv-tiles.
  const int bx = blockIdx.x;
  const int bh = blockIdx.y;
  const int qb = (bh >= 16) ? (15 - bx) : bx;
  const int nt = 2 * qb + 2;                  // kv tiles (64-wide) in causal span
  const size_t head_off = (size_t)bh * 2048 * 128;
  const unsigned short* Qh = Q + head_off;
  const unsigned short* Kh = K + head_off;
  const unsigned short* Vh = V + head_off;

  // ---- Q fragments: direct global->reg
  bf16x8 qf[2][4];
#pragma unroll
  for (int mi = 0; mi < 2; ++mi) {
    const int row = qb * 128 + w * 32 + mi * 16 + l15;
#pragma unroll
    for (int ks = 0; ks < 4; ++ks) {
      const int s = ks * 4 + g;
      qf[mi][ks] = *(const bf16x8*)(Qh + (size_t)row * 128 + s * 8);
    }
  }

  const int vj0 = (tid & 31) * 2;
  const int vd0 = (tid >> 5) * 16;
  u16x8 vr[4];

  auto stageK = [&](int t, int buf) {
#pragma unroll
    for (int it = 0; it < 4; ++it) {
      const int f = it * 256 + tid;
      const int r = f >> 4, s = f & 15;
      const int sc = s ^ (r & 7);             // inverse swizzle on SOURCE
      gload_lds16(Kh + (size_t)(t * 64 + r) * 128 + sc * 8,
                  (char*)&lK[buf][0] + (it * 256 + w * 64) * 16);
    }
  };
  auto loadV = [&](int t) {
    const unsigned short* vp = Vh + (size_t)(t * 64 + vj0) * 128 + vd0;
    vr[0] = *(const u16x8*)(vp);
    vr[1] = *(const u16x8*)(vp + 8);
    vr[2] = *(const u16x8*)(vp + 128);
    vr[3] = *(const u16x8*)(vp + 136);
  };
  auto writeV = [&]() {
#pragma unroll
    for (int dd = 0; dd < 8; ++dd) {
      unsigned pk0 = (unsigned)vr[0][dd] | ((unsigned)vr[2][dd] << 16);
      unsigned pk1 = (unsigned)vr[1][dd] | ((unsigned)vr[3][dd] << 16);
      *(unsigned*)&lV[(vd0 + dd) * 72 + vj0] = pk0;
      *(unsigned*)&lV[(vd0 + 8 + dd) * 72 + vj0] = pk1;
    }
  };

  // ---- prologue
  loadV(0);
  stageK(0, 0);
  writeV();
  __syncthreads();

  f32x4 acc_o[2][8];
#pragma unroll
  for (int mi = 0; mi < 2; ++mi)
#pragma unroll
    for (int i = 0; i < 8; ++i) acc_o[mi][i] = f32x4{0.f, 0.f, 0.f, 0.f};
  float mrun[2], lrun[2];                     // stats for column i = qrow0+16mi+l15
#pragma unroll
  for (int mi = 0; mi < 2; ++mi) { mrun[mi] = -__builtin_inff(); lrun[mi] = 0.f; }

  const float SL2E = 0.12751744f;             // (1/sqrt(128)) * log2(e)
  const int qrow0 = qb * 128 + w * 32;        // wave's first q-row

  int cur = 0;
  for (int t = 0; t < nt; ++t) {
    const int kv0 = t * 64;
    const bool pre = (t + 1 < nt);
    if (pre) { loadV(t + 1); stageK(t + 1, cur ^ 1); }   // prefetch under compute

    const bool active = (kv0 <= qrow0 + 31);  // wave-uniform
    if (active) {
      const unsigned short* lKc = &lK[cur][0];
      // ---- QK^T swapped: sacc[jb][mi] = S^T frags
      f32x4 sacc[4][2];
#pragma unroll
      for (int jb = 0; jb < 4; ++jb) {
        sacc[jb][0] = f32x4{0.f, 0.f, 0.f, 0.f};
        sacc[jb][1] = f32x4{0.f, 0.f, 0.f, 0.f};
      }
      __builtin_amdgcn_s_setprio(1);
#pragma unroll
      for (int jb = 0; jb < 4; ++jb) {
        const int r = jb * 16 + l15;
#pragma unroll
        for (int ks = 0; ks < 4; ++ks) {
          const int s = ks * 4 + g;
          bf16x8 kf = *(const bf16x8*)&lKc[r * 128 + (s ^ (r & 7)) * 8];
          sacc[jb][0] = MFMA16(kf, qf[0][ks], sacc[jb][0]);
          sacc[jb][1] = MFMA16(kf, qf[1][ks], sacc[jb][1]);
        }
      }
      __builtin_amdgcn_s_setprio(0);

      const bool need_mask = (kv0 + 63 >= qrow0);
      float psc_l[2];
#pragma unroll
      for (int mi = 0; mi < 2; ++mi) {
        // ---- scale + causal mask; j = kv0+16jb+4g+rr, i = qrow0+16mi+l15
        const int icol = qrow0 + mi * 16 + l15;
        f32x4 pe[4];
#pragma unroll
        for (int jb = 0; jb < 4; ++jb) {
#pragma unroll
          for (int rr = 0; rr < 4; ++rr) {
            float tv = sacc[jb][mi][rr] * SL2E;
            if (need_mask && (kv0 + jb * 16 + g * 4 + rr > icol))
              tv = -__builtin_inff();
            pe[jb][rr] = tv;
          }
        }
        // ---- in-lane max over 16, then cross-g butterflies
        f32x4 m4 = f32x4{fmaxf(fmaxf(pe[0][0], pe[1][0]), fmaxf(pe[2][0], pe[3][0])),
                         fmaxf(fmaxf(pe[0][1], pe[1][1]), fmaxf(pe[2][1], pe[3][1])),
                         fmaxf(fmaxf(pe[0][2], pe[1][2]), fmaxf(pe[2][2], pe[3][2])),
                         fmaxf(fmaxf(pe[0][3], pe[1][3]), fmaxf(pe[2][3], pe[3][3]))};
        float mx = fmaxf(fmaxf(m4[0], m4[1]), fmaxf(m4[2], m4[3]));
        mx = fmaxf(mx, __shfl_xor(mx, 16));
        mx = fmaxf(mx, __shfl_xor(mx, 32));
        const float mnew = fmaxf(mrun[mi], mx);
        psc_l[mi] = exp2f(mrun[mi] - mnew);   // 0 on first tile
        mrun[mi] = mnew;
        // ---- exp + row-sum
        float rs = 0.f;
#pragma unroll
        for (int jb = 0; jb < 4; ++jb) {
#pragma unroll
          for (int rr = 0; rr < 4; ++rr) {
            const float e = exp2f(pe[jb][rr] - mnew);
            pe[jb][rr] = e;
            rs += e;
          }
        }
        rs += __shfl_xor(rs, 16);
        rs += __shfl_xor(rs, 32);
        lrun[mi] = lrun[mi] * psc_l[mi] + rs;
        // ---- P -> per-wave LDS [i][j] (scalar u16 stores, r4-proven pattern)
#pragma unroll
        for (int jb = 0; jb < 4; ++jb)
#pragma unroll
          for (int rr = 0; rr < 4; ++rr)
            lP[w][(mi * 16 + l15) * 72 + jb * 16 + g * 4 + rr] = f2bf(pe[jb][rr]);
      }
      // fence: forbid hoisting the pa ds_reads above the lP ds_writes
      __builtin_amdgcn_sched_barrier(0);

      // ---- rescale acc_o: psc for PV rows i=4g+rr from lane l15=4g+rr
      float psc_pv[2][4];
#pragma unroll
      for (int mi = 0; mi < 2; ++mi)
#pragma unroll
        for (int r = 0; r < 4; ++r)
          psc_pv[mi][r] = __shfl(psc_l[mi], g * 4 + r);
#pragma unroll
      for (int mi = 0; mi < 2; ++mi)
#pragma unroll
        for (int nb = 0; nb < 8; ++nb)
#pragma unroll
          for (int r = 0; r < 4; ++r) acc_o[mi][nb][r] *= psc_pv[mi][r];

      // ---- PV: A = P frags from lP (row=i=l15, k=j), B = V^T rows from lV
      bf16x8 pa[2][2];
#pragma unroll
      for (int mi = 0; mi < 2; ++mi)
#pragma unroll
        for (int h = 0; h < 2; ++h)
          pa[mi][h] = *(const bf16x8*)&lP[w][(mi * 16 + l15) * 72 + h * 32 + g * 8];
      __builtin_amdgcn_s_setprio(1);
#pragma unroll
      for (int nb = 0; nb < 8; ++nb) {
        const int vrow = nb * 16 + l15;
#pragma unroll
        for (int h = 0; h < 2; ++h) {
          bf16x8 vf = *(const bf16x8*)&lV[vrow * 72 + h * 32 + g * 8];
          acc_o[0][nb] = MFMA16(pa[0][h], vf, acc_o[0][nb]);
          acc_o[1][nb] = MFMA16(pa[1][h], vf, acc_o[1][nb]);
        }
      }
      __builtin_amdgcn_s_setprio(0);
    }

    __syncthreads();          // all waves done reading lV(t), lK[cur]
    if (pre) writeV();        // V^T(t+1) -> lV (waits vmcnt for vr only)
    __syncthreads();          // lV(t+1) + lK[cur^1] ready
    cur ^= 1;
  }

  // ---- epilogue: O[b][i][h*128+d] bf16; lrun redistributed to PV row form
  const int b = bh >> 4, hh = bh & 15;
  float linv[2][4];
#pragma unroll
  for (int mi = 0; mi < 2; ++mi)
#pragma unroll
    for (int r = 0; r < 4; ++r)
      linv[mi][r] = 1.0f / __shfl(lrun[mi], g * 4 + r);
#pragma unroll
  for (int mi = 0; mi < 2; ++mi)
#pragma unroll
    for (int nb = 0; nb < 8; ++nb)
#pragma unroll
      for (int r = 0; r < 4; ++r) {
        const int i = qb * 128 + w * 32 + mi * 16 + g * 4 + r;
        const float o = acc_o[mi][nb][r] * linv[mi][r];
        O[((size_t)(b * 2048 + i)) * 2048 + hh * 128 + nb * 16 + l15] = f2bf(o);
      }
}

// ---------- launch ----------
extern "C" void kernel_launch(void* const* d_in, const int* in_sizes, int n_in,
                              void* d_out, int out_size, void* d_ws, size_t ws_size,
                              hipStream_t stream) {
  const float* x  = (const float*)d_in[0];
  const float* wq = (const float*)d_in[1];
  const float* bq = (const float*)d_in[2];
  const float* wk = (const float*)d_in[3];
  const float* bk = (const float*)d_in[4];
  const float* wv = (const float*)d_in[5];
  const float* bv = (const float*)d_in[6];
  const float* wo = (const float*)d_in[7];
  const float* bo = (const float*)d_in[8];

  const size_t NX = (size_t)2 * 2048 * 2048;
  const size_t NW = (size_t)2048 * 2048;
  const size_t need = (NX + 4 * NW + 3 * NX) * sizeof(unsigned short);  // 96 MB
  if (ws_size < need) return;
  unsigned short* xbf  = (unsigned short*)d_ws;
  unsigned short* wqb  = xbf + NX;
  unsigned short* wkb  = wqb + NW;
  unsigned short* wvb  = wkb + NW;
  unsigned short* wob  = wvb + NW;
  unsigned short* qbuf = wob + NW;
  unsigned short* kbuf = qbuf + NX;
  unsigned short* vbuf = kbuf + NX;
  unsigned short* aobuf = xbf;  // x dead after gemm_qkv (stream-ordered)

  cvt_all<<<dim3(4096, 6), 256, 0, stream>>>(x, wq, wk, wv, wo,
                                             xbf, wqb, wkb, wvb, wob);
  gemm_qkv<<<dim3(16, 32, 3), 256, 0, stream>>>(xbf, wqb, bq, wkb, bk, wvb, bv,
                                                qbuf, kbuf, vbuf);
  attn_fwd<<<dim3(16, 32), 256, 0, stream>>>(qbuf, kbuf, vbuf, aobuf);
  gemm_out<<<dim3(16, 32), 256, 0, stream>>>(aobuf, wob, bo, (float*)d_out);
}

// Round 7
// 292.044 us; speedup vs baseline: 1.3766x; 1.0227x over previous
//
#include <hip/hip_runtime.h>
#include <cstdint>
#include <cstddef>

// ---------- types / helpers ----------
typedef __attribute__((ext_vector_type(8))) short bf16x8;           // 8 bf16 = 4 VGPR
typedef __attribute__((ext_vector_type(8))) unsigned short u16x8;   // raw 16B load
typedef __attribute__((ext_vector_type(4))) unsigned short u16x4;   // 8B store
typedef __attribute__((ext_vector_type(4))) float f32x4;            // MFMA C/D

#define MFMA16(A, B, C) __builtin_amdgcn_mfma_f32_16x16x32_bf16((A), (B), (C), 0, 0, 0)

__device__ __forceinline__ unsigned short f2bf(float f) {
  unsigned u = __builtin_bit_cast(unsigned, f);
  u += 0x7FFFu + ((u >> 16) & 1u);   // RNE
  return (unsigned short)(u >> 16);
}

// global -> LDS async, 16B/lane. LDS dest wave-uniform (HW adds lane*16).
__device__ __forceinline__ void gload_lds16(const void* gsrc, void* ldst) {
  __builtin_amdgcn_global_load_lds(
      (const __attribute__((address_space(1))) unsigned int*)gsrc,
      (__attribute__((address_space(3))) unsigned int*)ldst,
      16, 0, 0);
}

// ---------- fused f32 -> bf16 down-convert (1 launch for x + 4 weights) ----------
__global__ __launch_bounds__(256) void cvt_all(
    const float* __restrict__ sx, const float* __restrict__ s1,
    const float* __restrict__ s2, const float* __restrict__ s3,
    const float* __restrict__ s4,
    unsigned short* __restrict__ dx, unsigned short* __restrict__ d1,
    unsigned short* __restrict__ d2, unsigned short* __restrict__ d3,
    unsigned short* __restrict__ d4) {
  const int y = blockIdx.y;
  const float* src;
  unsigned short* dst;
  if (y == 0)      { src = sx;               dst = dx; }
  else if (y == 1) { src = sx + (1u << 22);  dst = dx + (1u << 22); }
  else if (y == 2) { src = s1; dst = d1; }
  else if (y == 3) { src = s2; dst = d2; }
  else if (y == 4) { src = s3; dst = d3; }
  else             { src = s4; dst = d4; }
  const size_t i = ((size_t)blockIdx.x * 256 + threadIdx.x) * 4;
  f32x4 v = *(const f32x4*)(src + i);
  u16x4 o;
  o[0] = f2bf(v[0]); o[1] = f2bf(v[1]); o[2] = f2bf(v[2]); o[3] = f2bf(v[3]);
  *(u16x4*)(dst + i) = o;
}

// ---------- 8-phase GEMM: C[m][n] = sum_k A[m][k]*W[n][k] + bias[n] ----------
// BM=256, BN=128, BK=64; 8 waves (4M x 2N), per-wave 64x64 (acc[4][4]).
// Triple-buffered LDS (144KB): stage K-tile kt+2 while computing kt -> counted
// vmcnt(6) at K-tile boundaries (T3+T4). T2 XOR-swizzle: elem ^= (row&7)<<3,
// pre-swizzled gload SOURCE + swizzled ds_read (both-sides rule #21).
// 2 phases/K-tile x 16 MFMA (T5 setprio around clusters).
// MODE 0: C row-major f32. MODE 1: QKV head-permute bf16 [bh][s][dk].
template <int MODE>
__device__ __forceinline__ void gemm8_tile(const unsigned short* __restrict__ A,
                                           const unsigned short* __restrict__ W,
                                           const float* __restrict__ bias,
                                           void* __restrict__ C,
                                           int bx, int by) {
  constexpr int K = 2048, N = 2048;
  constexpr int NT = K / 64;                  // 32 K-tiles
  __shared__ unsigned short lA[3][256 * 64];  // 96KB
  __shared__ unsigned short lB[3][128 * 64];  // 48KB
  const int tid = threadIdx.x;
  const int lane = tid & 63;
  const int w = tid >> 6;                     // 0..7
  const int g = lane >> 4;
  const int l15 = lane & 15;
  const int wm = w >> 1, wn = w & 1;
  const int m0 = by * 256, n0 = bx * 128;

  auto stageA = [&](int kt, int buf) {        // 4 gloads: 256x64 = 2048 slots
    const int kb = kt * 64;
#pragma unroll
    for (int it = 0; it < 4; ++it) {
      const int f = it * 512 + tid;
      const int r = f >> 3, s = f & 7;
      gload_lds16(A + (size_t)(m0 + r) * K + kb + ((s * 8) ^ ((r & 7) << 3)),
                  (char*)&lA[buf][0] + (it * 512 + w * 64) * 16);
    }
  };
  auto stageB = [&](int kt, int buf) {        // 2 gloads: 128x64 = 1024 slots
    const int kb = kt * 64;
#pragma unroll
    for (int it = 0; it < 2; ++it) {
      const int f = it * 512 + tid;
      const int r = f >> 3, s = f & 7;
      gload_lds16(W + (size_t)(n0 + r) * K + kb + ((s * 8) ^ ((r & 7) << 3)),
                  (char*)&lB[buf][0] + (it * 512 + w * 64) * 16);
    }
  };

  f32x4 acc[4][4];
#pragma unroll
  for (int i = 0; i < 4; ++i)
#pragma unroll
    for (int j = 0; j < 4; ++j) acc[i][j] = f32x4{0.f, 0.f, 0.f, 0.f};

  // ---- prologue: tiles 0,1 -> bufs 0,1; wait tile0 (6 of 12 retire)
  stageA(0, 0); stageB(0, 0);
  stageA(1, 1); stageB(1, 1);
  asm volatile("s_waitcnt vmcnt(6)" ::: "memory");
  __builtin_amdgcn_s_barrier();
  __builtin_amdgcn_sched_barrier(0);

  int cur = 0, nxt = 2;
  for (int kt = 0; kt < NT; ++kt) {
    const unsigned short* As = &lA[cur][0];
    const unsigned short* Bs = &lB[cur][0];
    bf16x8 bfr[4][2], af[2][2];
    // ---- phase 0: ds_read B(all) + A(rows 0-1); stage A(kt+2); 16 MFMA
#pragma unroll
    for (int ni = 0; ni < 4; ++ni) {
      const int rb = wn * 64 + ni * 16 + l15;
#pragma unroll
      for (int kh = 0; kh < 2; ++kh)
        bfr[ni][kh] =
            *(const bf16x8*)&Bs[rb * 64 + ((kh * 32 + g * 8) ^ ((rb & 7) << 3))];
    }
#pragma unroll
    for (int mi = 0; mi < 2; ++mi) {
      const int ra = wm * 64 + mi * 16 + l15;
#pragma unroll
      for (int kh = 0; kh < 2; ++kh)
        af[mi][kh] =
            *(const bf16x8*)&As[ra * 64 + ((kh * 32 + g * 8) ^ ((ra & 7) << 3))];
    }
    if (kt + 2 < NT) stageA(kt + 2, nxt);
    __builtin_amdgcn_s_barrier();
    __builtin_amdgcn_sched_barrier(0);
    __builtin_amdgcn_s_setprio(1);
#pragma unroll
    for (int kh = 0; kh < 2; ++kh)
#pragma unroll
      for (int mi = 0; mi < 2; ++mi)
#pragma unroll
        for (int ni = 0; ni < 4; ++ni)
          acc[mi][ni] = MFMA16(af[mi][kh], bfr[ni][kh], acc[mi][ni]);
    __builtin_amdgcn_s_setprio(0);
    __builtin_amdgcn_s_barrier();
    __builtin_amdgcn_sched_barrier(0);
    // ---- phase 1: ds_read A(rows 2-3); stage B(kt+2); 16 MFMA; vmcnt; barrier
#pragma unroll
    for (int mi = 0; mi < 2; ++mi) {
      const int ra = wm * 64 + (mi + 2) * 16 + l15;
#pragma unroll
      for (int kh = 0; kh < 2; ++kh)
        af[mi][kh] =
            *(const bf16x8*)&As[ra * 64 + ((kh * 32 + g * 8) ^ ((ra & 7) << 3))];
    }
    if (kt + 2 < NT) stageB(kt + 2, nxt);
    __builtin_amdgcn_s_barrier();
    __builtin_amdgcn_sched_barrier(0);
    __builtin_amdgcn_s_setprio(1);
#pragma unroll
    for (int kh = 0; kh < 2; ++kh)
#pragma unroll
      for (int mi = 0; mi < 2; ++mi)
#pragma unroll
        for (int ni = 0; ni < 4; ++ni)
          acc[mi + 2][ni] = MFMA16(af[mi][kh], bfr[ni][kh], acc[mi + 2][ni]);
    __builtin_amdgcn_s_setprio(0);
    // tile kt+1 must be resident before next iter's ds_reads; keep kt+2's
    // 6 loads in flight (T4 counted vmcnt, never 0 mid-loop).
    if (kt < NT - 2)       asm volatile("s_waitcnt vmcnt(6)" ::: "memory");
    else if (kt == NT - 2) asm volatile("s_waitcnt vmcnt(0)" ::: "memory");
    __builtin_amdgcn_s_barrier();
    __builtin_amdgcn_sched_barrier(0);
    cur = (cur == 2) ? 0 : cur + 1;
    nxt = (nxt == 2) ? 0 : nxt + 1;
  }

  // ---- epilogue: D layout col=lane&15 (n), row=4g+rr (m)
#pragma unroll
  for (int ni = 0; ni < 4; ++ni) {
    const int n = n0 + wn * 64 + ni * 16 + l15;
    const float bval = bias[n];
#pragma unroll
    for (int mi = 0; mi < 4; ++mi) {
      const int mb = m0 + wm * 64 + mi * 16 + g * 4;
#pragma unroll
      for (int r = 0; r < 4; ++r) {
        const int m = mb + r;
        const float fv = acc[mi][ni][r] + bval;
        if (MODE == 0) {
          ((float*)C)[(size_t)m * N + n] = fv;
        } else {
          const int bb = m >> 11, ss = m & 2047, hh = n >> 7, dk = n & 127;
          ((unsigned short*)C)[(((size_t)(bb * 16 + hh) * 2048) + ss) * 128 + dk] =
              f2bf(fv);
        }
      }
    }
  }
}

__global__ __launch_bounds__(512, 2) void gemm_qkv(
    const unsigned short* __restrict__ x,
    const unsigned short* __restrict__ wq, const float* __restrict__ bq,
    const unsigned short* __restrict__ wk, const float* __restrict__ bk,
    const unsigned short* __restrict__ wv, const float* __restrict__ bv,
    unsigned short* __restrict__ qo, unsigned short* __restrict__ ko,
    unsigned short* __restrict__ vo) {
  const int z = blockIdx.z;
  const unsigned short* W = (z == 0) ? wq : (z == 1) ? wk : wv;
  const float* B = (z == 0) ? bq : (z == 1) ? bk : bv;
  unsigned short* O = (z == 0) ? qo : (z == 1) ? ko : vo;
  gemm8_tile<1>(x, W, B, O, blockIdx.x, blockIdx.y);
}

__global__ __launch_bounds__(512, 2) void gemm_out(
    const unsigned short* __restrict__ A, const unsigned short* __restrict__ wo,
    const float* __restrict__ bo, float* __restrict__ C) {
  gemm8_tile<0>(A, wo, bo, C, blockIdx.x, blockIdx.y);
}

// ---------- causal flash attention, swapped-QK^T in-lane softmax (r6 proven) ----------
__global__ __launch_bounds__(256, 2) void attn_fwd(
    const unsigned short* __restrict__ Q, const unsigned short* __restrict__ K,
    const unsigned short* __restrict__ V, unsigned short* __restrict__ O) {
  __shared__ unsigned short lK[2][64 * 128];  // 32KB dbuf (swizzled slots)
  __shared__ unsigned short lV[128 * 72];     // V^T [d][j], 144B rows
  __shared__ unsigned short lP[4][32 * 72];   // per-wave P [i][j], 144B rows
  const int tid = threadIdx.x;
  const int lane = tid & 63;
  const int w = tid >> 6;
  const int g = lane >> 4;
  const int l15 = lane & 15;
  const int bx = blockIdx.x;
  const int bh = blockIdx.y;
  const int qb = (bh >= 16) ? (15 - bx) : bx;  // CU-pair balance
  const int nt = 2 * qb + 2;
  const size_t head_off = (size_t)bh * 2048 * 128;
  const unsigned short* Qh = Q + head_off;
  const unsigned short* Kh = K + head_off;
  const unsigned short* Vh = V + head_off;

  bf16x8 qf[2][4];
#pragma unroll
  for (int mi = 0; mi < 2; ++mi) {
    const int row = qb * 128 + w * 32 + mi * 16 + l15;
#pragma unroll
    for (int ks = 0; ks < 4; ++ks) {
      const int s = ks * 4 + g;
      qf[mi][ks] = *(const bf16x8*)(Qh + (size_t)row * 128 + s * 8);
    }
  }

  const int vj0 = (tid & 31) * 2;
  const int vd0 = (tid >> 5) * 16;
  u16x8 vr[4];

  auto stageK = [&](int t, int buf) {
#pragma unroll
    for (int it = 0; it < 4; ++it) {
      const int f = it * 256 + tid;
      const int r = f >> 4, s = f & 15;
      const int sc = s ^ (r & 7);
      gload_lds16(Kh + (size_t)(t * 64 + r) * 128 + sc * 8,
                  (char*)&lK[buf][0] + (it * 256 + w * 64) * 16);
    }
  };
  auto loadV = [&](int t) {
    const unsigned short* vp = Vh + (size_t)(t * 64 + vj0) * 128 + vd0;
    vr[0] = *(const u16x8*)(vp);
    vr[1] = *(const u16x8*)(vp + 8);
    vr[2] = *(const u16x8*)(vp + 128);
    vr[3] = *(const u16x8*)(vp + 136);
  };
  auto writeV = [&]() {
#pragma unroll
    for (int dd = 0; dd < 8; ++dd) {
      unsigned pk0 = (unsigned)vr[0][dd] | ((unsigned)vr[2][dd] << 16);
      unsigned pk1 = (unsigned)vr[1][dd] | ((unsigned)vr[3][dd] << 16);
      *(unsigned*)&lV[(vd0 + dd) * 72 + vj0] = pk0;
      *(unsigned*)&lV[(vd0 + 8 + dd) * 72 + vj0] = pk1;
    }
  };

  loadV(0);
  stageK(0, 0);
  writeV();
  __syncthreads();

  f32x4 acc_o[2][8];
#pragma unroll
  for (int mi = 0; mi < 2; ++mi)
#pragma unroll
    for (int i = 0; i < 8; ++i) acc_o[mi][i] = f32x4{0.f, 0.f, 0.f, 0.f};
  float mrun[2], lrun[2];
#pragma unroll
  for (int mi = 0; mi < 2; ++mi) { mrun[mi] = -__builtin_inff(); lrun[mi] = 0.f; }

  const float SL2E = 0.12751744f;
  const int qrow0 = qb * 128 + w * 32;

  int cur = 0;
  for (int t = 0; t < nt; ++t) {
    const int kv0 = t * 64;
    const bool pre = (t + 1 < nt);
    if (pre) { loadV(t + 1); stageK(t + 1, cur ^ 1); }

    const bool active = (kv0 <= qrow0 + 31);
    if (active) {
      const unsigned short* lKc = &lK[cur][0];
      f32x4 sacc[4][2];
#pragma unroll
      for (int jb = 0; jb < 4; ++jb) {
        sacc[jb][0] = f32x4{0.f, 0.f, 0.f, 0.f};
        sacc[jb][1] = f32x4{0.f, 0.f, 0.f, 0.f};
      }
      __builtin_amdgcn_s_setprio(1);
#pragma unroll
      for (int jb = 0; jb < 4; ++jb) {
        const int r = jb * 16 + l15;
#pragma unroll
        for (int ks = 0; ks < 4; ++ks) {
          const int s = ks * 4 + g;
          bf16x8 kf = *(const bf16x8*)&lKc[r * 128 + (s ^ (r & 7)) * 8];
          sacc[jb][0] = MFMA16(kf, qf[0][ks], sacc[jb][0]);
          sacc[jb][1] = MFMA16(kf, qf[1][ks], sacc[jb][1]);
        }
      }
      __builtin_amdgcn_s_setprio(0);

      const bool need_mask = (kv0 + 63 >= qrow0);
      float psc_l[2];
#pragma unroll
      for (int mi = 0; mi < 2; ++mi) {
        const int icol = qrow0 + mi * 16 + l15;
        f32x4 pe[4];
#pragma unroll
        for (int jb = 0; jb < 4; ++jb) {
#pragma unroll
          for (int rr = 0; rr < 4; ++rr) {
            float tv = sacc[jb][mi][rr] * SL2E;
            if (need_mask && (kv0 + jb * 16 + g * 4 + rr > icol))
              tv = -__builtin_inff();
            pe[jb][rr] = tv;
          }
        }
        f32x4 m4 = f32x4{fmaxf(fmaxf(pe[0][0], pe[1][0]), fmaxf(pe[2][0], pe[3][0])),
                         fmaxf(fmaxf(pe[0][1], pe[1][1]), fmaxf(pe[2][1], pe[3][1])),
                         fmaxf(fmaxf(pe[0][2], pe[1][2]), fmaxf(pe[2][2], pe[3][2])),
                         fmaxf(fmaxf(pe[0][3], pe[1][3]), fmaxf(pe[2][3], pe[3][3]))};
        float mx = fmaxf(fmaxf(m4[0], m4[1]), fmaxf(m4[2], m4[3]));
        mx = fmaxf(mx, __shfl_xor(mx, 16));
        mx = fmaxf(mx, __shfl_xor(mx, 32));
        const float mnew = fmaxf(mrun[mi], mx);
        psc_l[mi] = exp2f(mrun[mi] - mnew);
        mrun[mi] = mnew;
        float rs = 0.f;
#pragma unroll
        for (int jb = 0; jb < 4; ++jb) {
#pragma unroll
          for (int rr = 0; rr < 4; ++rr) {
            const float e = exp2f(pe[jb][rr] - mnew);
            pe[jb][rr] = e;
            rs += e;
          }
        }
        rs += __shfl_xor(rs, 16);
        rs += __shfl_xor(rs, 32);
        lrun[mi] = lrun[mi] * psc_l[mi] + rs;
#pragma unroll
        for (int jb = 0; jb < 4; ++jb)
#pragma unroll
          for (int rr = 0; rr < 4; ++rr)
            lP[w][(mi * 16 + l15) * 72 + jb * 16 + g * 4 + rr] = f2bf(pe[jb][rr]);
      }
      __builtin_amdgcn_sched_barrier(0);

      float psc_pv[2][4];
#pragma unroll
      for (int mi = 0; mi < 2; ++mi)
#pragma unroll
        for (int r = 0; r < 4; ++r)
          psc_pv[mi][r] = __shfl(psc_l[mi], g * 4 + r);
#pragma unroll
      for (int mi = 0; mi < 2; ++mi)
#pragma unroll
        for (int nb = 0; nb < 8; ++nb)
#pragma unroll
          for (int r = 0; r < 4; ++r) acc_o[mi][nb][r] *= psc_pv[mi][r];

      bf16x8 pa[2][2];
#pragma unroll
      for (int mi = 0; mi < 2; ++mi)
#pragma unroll
        for (int h = 0; h < 2; ++h)
          pa[mi][h] = *(const bf16x8*)&lP[w][(mi * 16 + l15) * 72 + h * 32 + g * 8];
      __builtin_amdgcn_s_setprio(1);
#pragma unroll
      for (int nb = 0; nb < 8; ++nb) {
        const int vrow = nb * 16 + l15;
#pragma unroll
        for (int h = 0; h < 2; ++h) {
          bf16x8 vf = *(const bf16x8*)&lV[vrow * 72 + h * 32 + g * 8];
          acc_o[0][nb] = MFMA16(pa[0][h], vf, acc_o[0][nb]);
          acc_o[1][nb] = MFMA16(pa[1][h], vf, acc_o[1][nb]);
        }
      }
      __builtin_amdgcn_s_setprio(0);
    }

    __syncthreads();
    if (pre) writeV();
    __syncthreads();
    cur ^= 1;
  }

  const int b = bh >> 4, hh = bh & 15;
  float linv[2][4];
#pragma unroll
  for (int mi = 0; mi < 2; ++mi)
#pragma unroll
    for (int r = 0; r < 4; ++r)
      linv[mi][r] = 1.0f / __shfl(lrun[mi], g * 4 + r);
#pragma unroll
  for (int mi = 0; mi < 2; ++mi)
#pragma unroll
    for (int nb = 0; nb < 8; ++nb)
#pragma unroll
      for (int r = 0; r < 4; ++r) {
        const int i = qb * 128 + w * 32 + mi * 16 + g * 4 + r;
        const float o = acc_o[mi][nb][r] * linv[mi][r];
        O[((size_t)(b * 2048 + i)) * 2048 + hh * 128 + nb * 16 + l15] = f2bf(o);
      }
}

// ---------- launch ----------
extern "C" void kernel_launch(void* const* d_in, const int* in_sizes, int n_in,
                              void* d_out, int out_size, void* d_ws, size_t ws_size,
                              hipStream_t stream) {
  const float* x  = (const float*)d_in[0];
  const float* wq = (const float*)d_in[1];
  const float* bq = (const float*)d_in[2];
  const float* wk = (const float*)d_in[3];
  const float* bk = (const float*)d_in[4];
  const float* wv = (const float*)d_in[5];
  const float* bv = (const float*)d_in[6];
  const float* wo = (const float*)d_in[7];
  const float* bo = (const float*)d_in[8];

  const size_t NX = (size_t)2 * 2048 * 2048;
  const size_t NW = (size_t)2048 * 2048;
  const size_t need = (NX + 4 * NW + 3 * NX) * sizeof(unsigned short);  // 96 MB
  if (ws_size < need) return;
  unsigned short* xbf  = (unsigned short*)d_ws;
  unsigned short* wqb  = xbf + NX;
  unsigned short* wkb  = wqb + NW;
  unsigned short* wvb  = wkb + NW;
  unsigned short* wob  = wvb + NW;
  unsigned short* qbuf = wob + NW;
  unsigned short* kbuf = qbuf + NX;
  unsigned short* vbuf = kbuf + NX;
  unsigned short* aobuf = xbf;  // x dead after gemm_qkv (stream-ordered)

  cvt_all<<<dim3(4096, 6), 256, 0, stream>>>(x, wq, wk, wv, wo,
                                             xbf, wqb, wkb, wvb, wob);
  // 8-phase GEMMs: BM=256 -> grid.y = 4096/256 = 16; BN=128 -> grid.x = 16
  gemm_qkv<<<dim3(16, 16, 3), 512, 0, stream>>>(xbf, wqb, bq, wkb, bk, wvb, bv,
                                                qbuf, kbuf, vbuf);
  attn_fwd<<<dim3(16, 32), 256, 0, stream>>>(qbuf, kbuf, vbuf, aobuf);
  gemm_out<<<dim3(16, 16), 512, 0, stream>>>(aobuf, wob, bo, (float*)d_out);
}

// Round 8
// 291.463 us; speedup vs baseline: 1.3794x; 1.0020x over previous
//
#include <hip/hip_runtime.h>
#include <cstdint>
#include <cstddef>

// ---------- types / helpers ----------
typedef __attribute__((ext_vector_type(8))) short bf16x8;           // 8 bf16 = 4 VGPR
typedef __attribute__((ext_vector_type(8))) unsigned short u16x8;   // raw 16B load
typedef __attribute__((ext_vector_type(4))) unsigned short u16x4;   // 8B store
typedef __attribute__((ext_vector_type(4))) float f32x4;            // MFMA C/D

#define MFMA16(A, B, C) __builtin_amdgcn_mfma_f32_16x16x32_bf16((A), (B), (C), 0, 0, 0)

__device__ __forceinline__ unsigned short f2bf(float f) {
  unsigned u = __builtin_bit_cast(unsigned, f);
  u += 0x7FFFu + ((u >> 16) & 1u);   // RNE
  return (unsigned short)(u >> 16);
}

// global -> LDS async, 16B/lane. LDS dest wave-uniform (HW adds lane*16).
__device__ __forceinline__ void gload_lds16(const void* gsrc, void* ldst) {
  __builtin_amdgcn_global_load_lds(
      (const __attribute__((address_space(1))) unsigned int*)gsrc,
      (__attribute__((address_space(3))) unsigned int*)ldst,
      16, 0, 0);
}

// ---------- fused f32 -> bf16 down-convert (1 launch for x + 4 weights) ----------
__global__ __launch_bounds__(256) void cvt_all(
    const float* __restrict__ sx, const float* __restrict__ s1,
    const float* __restrict__ s2, const float* __restrict__ s3,
    const float* __restrict__ s4,
    unsigned short* __restrict__ dx, unsigned short* __restrict__ d1,
    unsigned short* __restrict__ d2, unsigned short* __restrict__ d3,
    unsigned short* __restrict__ d4) {
  const int y = blockIdx.y;
  const float* src;
  unsigned short* dst;
  if (y == 0)      { src = sx;               dst = dx; }
  else if (y == 1) { src = sx + (1u << 22);  dst = dx + (1u << 22); }
  else if (y == 2) { src = s1; dst = d1; }
  else if (y == 3) { src = s2; dst = d2; }
  else if (y == 4) { src = s3; dst = d3; }
  else             { src = s4; dst = d4; }
  const size_t i = ((size_t)blockIdx.x * 256 + threadIdx.x) * 4;
  f32x4 v = *(const f32x4*)(src + i);
  u16x4 o;
  o[0] = f2bf(v[0]); o[1] = f2bf(v[1]); o[2] = f2bf(v[2]); o[3] = f2bf(v[3]);
  *(u16x4*)(dst + i) = o;
}

// ---------- 8-phase GEMM: C[m][n] = sum_k A[m][k]*W[n][k] + bias[n] ----------
// BM=256, BN=128, BK=64; 8 waves (4M x 2N), per-wave 64x64 (acc[4][4]).
// Triple-buffered LDS (144KB): stage K-tile kt+2 while computing kt -> counted
// vmcnt(6) at K-tile boundaries (T3+T4). T2 XOR-swizzle: elem ^= (row&7)<<3,
// pre-swizzled gload SOURCE + swizzled ds_read (both-sides rule #21).
// MODE 0: C row-major f32. MODE 1: QKV head-permute bf16 [bh][s][dk].
template <int MODE>
__device__ __forceinline__ void gemm8_tile(const unsigned short* __restrict__ A,
                                           const unsigned short* __restrict__ W,
                                           const float* __restrict__ bias,
                                           void* __restrict__ C,
                                           int bx, int by) {
  constexpr int K = 2048, N = 2048;
  constexpr int NT = K / 64;                  // 32 K-tiles
  __shared__ unsigned short lA[3][256 * 64];  // 96KB
  __shared__ unsigned short lB[3][128 * 64];  // 48KB
  const int tid = threadIdx.x;
  const int lane = tid & 63;
  const int w = tid >> 6;                     // 0..7
  const int g = lane >> 4;
  const int l15 = lane & 15;
  const int wm = w >> 1, wn = w & 1;
  const int m0 = by * 256, n0 = bx * 128;

  auto stageA = [&](int kt, int buf) {        // 4 gloads: 256x64 = 2048 slots
    const int kb = kt * 64;
#pragma unroll
    for (int it = 0; it < 4; ++it) {
      const int f = it * 512 + tid;
      const int r = f >> 3, s = f & 7;
      gload_lds16(A + (size_t)(m0 + r) * K + kb + ((s * 8) ^ ((r & 7) << 3)),
                  (char*)&lA[buf][0] + (it * 512 + w * 64) * 16);
    }
  };
  auto stageB = [&](int kt, int buf) {        // 2 gloads: 128x64 = 1024 slots
    const int kb = kt * 64;
#pragma unroll
    for (int it = 0; it < 2; ++it) {
      const int f = it * 512 + tid;
      const int r = f >> 3, s = f & 7;
      gload_lds16(W + (size_t)(n0 + r) * K + kb + ((s * 8) ^ ((r & 7) << 3)),
                  (char*)&lB[buf][0] + (it * 512 + w * 64) * 16);
    }
  };

  f32x4 acc[4][4];
#pragma unroll
  for (int i = 0; i < 4; ++i)
#pragma unroll
    for (int j = 0; j < 4; ++j) acc[i][j] = f32x4{0.f, 0.f, 0.f, 0.f};

  // ---- prologue: tiles 0,1 -> bufs 0,1; wait tile0 (6 of 12 retire)
  stageA(0, 0); stageB(0, 0);
  stageA(1, 1); stageB(1, 1);
  asm volatile("s_waitcnt vmcnt(6)" ::: "memory");
  __builtin_amdgcn_s_barrier();
  __builtin_amdgcn_sched_barrier(0);

  int cur = 0, nxt = 2;
  for (int kt = 0; kt < NT; ++kt) {
    const unsigned short* As = &lA[cur][0];
    const unsigned short* Bs = &lB[cur][0];
    bf16x8 bfr[4][2], af[2][2];
    // ---- phase 0: ds_read B(all) + A(rows 0-1); stage A(kt+2); 16 MFMA
#pragma unroll
    for (int ni = 0; ni < 4; ++ni) {
      const int rb = wn * 64 + ni * 16 + l15;
#pragma unroll
      for (int kh = 0; kh < 2; ++kh)
        bfr[ni][kh] =
            *(const bf16x8*)&Bs[rb * 64 + ((kh * 32 + g * 8) ^ ((rb & 7) << 3))];
    }
#pragma unroll
    for (int mi = 0; mi < 2; ++mi) {
      const int ra = wm * 64 + mi * 16 + l15;
#pragma unroll
      for (int kh = 0; kh < 2; ++kh)
        af[mi][kh] =
            *(const bf16x8*)&As[ra * 64 + ((kh * 32 + g * 8) ^ ((ra & 7) << 3))];
    }
    if (kt + 2 < NT) stageA(kt + 2, nxt);
    __builtin_amdgcn_s_barrier();
    __builtin_amdgcn_sched_barrier(0);
    __builtin_amdgcn_s_setprio(1);
#pragma unroll
    for (int kh = 0; kh < 2; ++kh)
#pragma unroll
      for (int mi = 0; mi < 2; ++mi)
#pragma unroll
        for (int ni = 0; ni < 4; ++ni)
          acc[mi][ni] = MFMA16(af[mi][kh], bfr[ni][kh], acc[mi][ni]);
    __builtin_amdgcn_s_setprio(0);
    __builtin_amdgcn_s_barrier();
    __builtin_amdgcn_sched_barrier(0);
    // ---- phase 1: ds_read A(rows 2-3); stage B(kt+2); 16 MFMA; vmcnt; barrier
#pragma unroll
    for (int mi = 0; mi < 2; ++mi) {
      const int ra = wm * 64 + (mi + 2) * 16 + l15;
#pragma unroll
      for (int kh = 0; kh < 2; ++kh)
        af[mi][kh] =
            *(const bf16x8*)&As[ra * 64 + ((kh * 32 + g * 8) ^ ((ra & 7) << 3))];
    }
    if (kt + 2 < NT) stageB(kt + 2, nxt);
    __builtin_amdgcn_s_barrier();
    __builtin_amdgcn_sched_barrier(0);
    __builtin_amdgcn_s_setprio(1);
#pragma unroll
    for (int kh = 0; kh < 2; ++kh)
#pragma unroll
      for (int mi = 0; mi < 2; ++mi)
#pragma unroll
        for (int ni = 0; ni < 4; ++ni)
          acc[mi + 2][ni] = MFMA16(af[mi][kh], bfr[ni][kh], acc[mi + 2][ni]);
    __builtin_amdgcn_s_setprio(0);
    // tile kt+1 must be resident before next iter's ds_reads; keep kt+2's
    // 6 loads in flight (T4 counted vmcnt, never 0 mid-loop).
    if (kt < NT - 2)       asm volatile("s_waitcnt vmcnt(6)" ::: "memory");
    else if (kt == NT - 2) asm volatile("s_waitcnt vmcnt(0)" ::: "memory");
    __builtin_amdgcn_s_barrier();
    __builtin_amdgcn_sched_barrier(0);
    cur = (cur == 2) ? 0 : cur + 1;
    nxt = (nxt == 2) ? 0 : nxt + 1;
  }

  // ---- epilogue: D layout col=lane&15 (n), row=4g+rr (m)
#pragma unroll
  for (int ni = 0; ni < 4; ++ni) {
    const int n = n0 + wn * 64 + ni * 16 + l15;
    const float bval = bias[n];
#pragma unroll
    for (int mi = 0; mi < 4; ++mi) {
      const int mb = m0 + wm * 64 + mi * 16 + g * 4;
#pragma unroll
      for (int r = 0; r < 4; ++r) {
        const int m = mb + r;
        const float fv = acc[mi][ni][r] + bval;
        if (MODE == 0) {
          ((float*)C)[(size_t)m * N + n] = fv;
        } else {
          const int bb = m >> 11, ss = m & 2047, hh = n >> 7, dk = n & 127;
          ((unsigned short*)C)[(((size_t)(bb * 16 + hh) * 2048) + ss) * 128 + dk] =
              f2bf(fv);
        }
      }
    }
  }
}

// T1 XCD-aware bijective remap: blocks resident on one XCD (o%8 const) cover a
// compact by-major tile range -> A-panels L2-local, working set L3-local.
__global__ __launch_bounds__(512, 2) void gemm_qkv(
    const unsigned short* __restrict__ x,
    const unsigned short* __restrict__ wq, const float* __restrict__ bq,
    const unsigned short* __restrict__ wk, const float* __restrict__ bk,
    const unsigned short* __restrict__ wv, const float* __restrict__ bv,
    unsigned short* __restrict__ qo, unsigned short* __restrict__ ko,
    unsigned short* __restrict__ vo) {
  const int o = blockIdx.x + ((int)blockIdx.y << 4) + ((int)blockIdx.z << 8);
  const int t = (o & 7) * 96 + (o >> 3);      // 768 = 8 x 96, bijective
  const int z = t >> 8;
  const int by = (t & 255) >> 4;
  const int bx = t & 15;
  const unsigned short* W = (z == 0) ? wq : (z == 1) ? wk : wv;
  const float* B = (z == 0) ? bq : (z == 1) ? bk : bv;
  unsigned short* O = (z == 0) ? qo : (z == 1) ? ko : vo;
  gemm8_tile<1>(x, W, B, O, bx, by);
}

__global__ __launch_bounds__(512, 2) void gemm_out(
    const unsigned short* __restrict__ A, const unsigned short* __restrict__ wo,
    const float* __restrict__ bo, float* __restrict__ C) {
  const int o = blockIdx.x + ((int)blockIdx.y << 4);
  const int t = (o & 7) * 32 + (o >> 3);      // 256 = 8 x 32, bijective
  const int by = t >> 4;
  const int bx = t & 15;
  gemm8_tile<0>(A, wo, bo, C, bx, by);
}

// ---------- causal flash attention, swapped-QK^T in-lane softmax (r6 proven) ----------
__global__ __launch_bounds__(256, 2) void attn_fwd(
    const unsigned short* __restrict__ Q, const unsigned short* __restrict__ K,
    const unsigned short* __restrict__ V, unsigned short* __restrict__ O) {
  __shared__ unsigned short lK[2][64 * 128];  // 32KB dbuf (swizzled slots)
  __shared__ unsigned short lV[128 * 72];     // V^T [d][j], 144B rows
  __shared__ unsigned short lP[4][32 * 72];   // per-wave P [i][j], 144B rows
  const int tid = threadIdx.x;
  const int lane = tid & 63;
  const int w = tid >> 6;
  const int g = lane >> 4;
  const int l15 = lane & 15;
  const int bx = blockIdx.x;
  const int bh = blockIdx.y;
  const int qb = (bh >= 16) ? (15 - bx) : bx;  // CU-pair balance
  const int nt = 2 * qb + 2;
  const size_t head_off = (size_t)bh * 2048 * 128;
  const unsigned short* Qh = Q + head_off;
  const unsigned short* Kh = K + head_off;
  const unsigned short* Vh = V + head_off;

  bf16x8 qf[2][4];
#pragma unroll
  for (int mi = 0; mi < 2; ++mi) {
    const int row = qb * 128 + w * 32 + mi * 16 + l15;
#pragma unroll
    for (int ks = 0; ks < 4; ++ks) {
      const int s = ks * 4 + g;
      qf[mi][ks] = *(const bf16x8*)(Qh + (size_t)row * 128 + s * 8);
    }
  }

  const int vj0 = (tid & 31) * 2;
  const int vd0 = (tid >> 5) * 16;
  u16x8 vr[4];

  auto stageK = [&](int t, int buf) {
#pragma unroll
    for (int it = 0; it < 4; ++it) {
      const int f = it * 256 + tid;
      const int r = f >> 4, s = f & 15;
      const int sc = s ^ (r & 7);
      gload_lds16(Kh + (size_t)(t * 64 + r) * 128 + sc * 8,
                  (char*)&lK[buf][0] + (it * 256 + w * 64) * 16);
    }
  };
  auto loadV = [&](int t) {
    const unsigned short* vp = Vh + (size_t)(t * 64 + vj0) * 128 + vd0;
    vr[0] = *(const u16x8*)(vp);
    vr[1] = *(const u16x8*)(vp + 8);
    vr[2] = *(const u16x8*)(vp + 128);
    vr[3] = *(const u16x8*)(vp + 136);
  };
  auto writeV = [&]() {
#pragma unroll
    for (int dd = 0; dd < 8; ++dd) {
      unsigned pk0 = (unsigned)vr[0][dd] | ((unsigned)vr[2][dd] << 16);
      unsigned pk1 = (unsigned)vr[1][dd] | ((unsigned)vr[3][dd] << 16);
      *(unsigned*)&lV[(vd0 + dd) * 72 + vj0] = pk0;
      *(unsigned*)&lV[(vd0 + 8 + dd) * 72 + vj0] = pk1;
    }
  };

  loadV(0);
  stageK(0, 0);
  writeV();
  __syncthreads();

  f32x4 acc_o[2][8];
#pragma unroll
  for (int mi = 0; mi < 2; ++mi)
#pragma unroll
    for (int i = 0; i < 8; ++i) acc_o[mi][i] = f32x4{0.f, 0.f, 0.f, 0.f};
  float mrun[2], lrun[2];
#pragma unroll
  for (int mi = 0; mi < 2; ++mi) { mrun[mi] = -__builtin_inff(); lrun[mi] = 0.f; }

  const float SL2E = 0.12751744f;
  const int qrow0 = qb * 128 + w * 32;

  int cur = 0;
  for (int t = 0; t < nt; ++t) {
    const int kv0 = t * 64;
    const bool pre = (t + 1 < nt);
    if (pre) { loadV(t + 1); stageK(t + 1, cur ^ 1); }

    const bool active = (kv0 <= qrow0 + 31);
    if (active) {
      const unsigned short* lKc = &lK[cur][0];
      f32x4 sacc[4][2];
#pragma unroll
      for (int jb = 0; jb < 4; ++jb) {
        sacc[jb][0] = f32x4{0.f, 0.f, 0.f, 0.f};
        sacc[jb][1] = f32x4{0.f, 0.f, 0.f, 0.f};
      }
      __builtin_amdgcn_s_setprio(1);
#pragma unroll
      for (int jb = 0; jb < 4; ++jb) {
        const int r = jb * 16 + l15;
#pragma unroll
        for (int ks = 0; ks < 4; ++ks) {
          const int s = ks * 4 + g;
          bf16x8 kf = *(const bf16x8*)&lKc[r * 128 + (s ^ (r & 7)) * 8];
          sacc[jb][0] = MFMA16(kf, qf[0][ks], sacc[jb][0]);
          sacc[jb][1] = MFMA16(kf, qf[1][ks], sacc[jb][1]);
        }
      }
      __builtin_amdgcn_s_setprio(0);

      const bool need_mask = (kv0 + 63 >= qrow0);
      float psc_l[2];
#pragma unroll
      for (int mi = 0; mi < 2; ++mi) {
        const int icol = qrow0 + mi * 16 + l15;
        f32x4 pe[4];
#pragma unroll
        for (int jb = 0; jb < 4; ++jb) {
#pragma unroll
          for (int rr = 0; rr < 4; ++rr) {
            float tv = sacc[jb][mi][rr] * SL2E;
            if (need_mask && (kv0 + jb * 16 + g * 4 + rr > icol))
              tv = -__builtin_inff();
            pe[jb][rr] = tv;
          }
        }
        f32x4 m4 = f32x4{fmaxf(fmaxf(pe[0][0], pe[1][0]), fmaxf(pe[2][0], pe[3][0])),
                         fmaxf(fmaxf(pe[0][1], pe[1][1]), fmaxf(pe[2][1], pe[3][1])),
                         fmaxf(fmaxf(pe[0][2], pe[1][2]), fmaxf(pe[2][2], pe[3][2])),
                         fmaxf(fmaxf(pe[0][3], pe[1][3]), fmaxf(pe[2][3], pe[3][3]))};
        float mx = fmaxf(fmaxf(m4[0], m4[1]), fmaxf(m4[2], m4[3]));
        mx = fmaxf(mx, __shfl_xor(mx, 16));
        mx = fmaxf(mx, __shfl_xor(mx, 32));
        const float mnew = fmaxf(mrun[mi], mx);
        psc_l[mi] = exp2f(mrun[mi] - mnew);
        mrun[mi] = mnew;
        float rs = 0.f;
#pragma unroll
        for (int jb = 0; jb < 4; ++jb) {
#pragma unroll
          for (int rr = 0; rr < 4; ++rr) {
            const float e = exp2f(pe[jb][rr] - mnew);
            pe[jb][rr] = e;
            rs += e;
          }
        }
        rs += __shfl_xor(rs, 16);
        rs += __shfl_xor(rs, 32);
        lrun[mi] = lrun[mi] * psc_l[mi] + rs;
#pragma unroll
        for (int jb = 0; jb < 4; ++jb)
#pragma unroll
          for (int rr = 0; rr < 4; ++rr)
            lP[w][(mi * 16 + l15) * 72 + jb * 16 + g * 4 + rr] = f2bf(pe[jb][rr]);
      }
      __builtin_amdgcn_sched_barrier(0);

      float psc_pv[2][4];
#pragma unroll
      for (int mi = 0; mi < 2; ++mi)
#pragma unroll
        for (int r = 0; r < 4; ++r)
          psc_pv[mi][r] = __shfl(psc_l[mi], g * 4 + r);
#pragma unroll
      for (int mi = 0; mi < 2; ++mi)
#pragma unroll
        for (int nb = 0; nb < 8; ++nb)
#pragma unroll
          for (int r = 0; r < 4; ++r) acc_o[mi][nb][r] *= psc_pv[mi][r];

      bf16x8 pa[2][2];
#pragma unroll
      for (int mi = 0; mi < 2; ++mi)
#pragma unroll
        for (int h = 0; h < 2; ++h)
          pa[mi][h] = *(const bf16x8*)&lP[w][(mi * 16 + l15) * 72 + h * 32 + g * 8];
      __builtin_amdgcn_s_setprio(1);
#pragma unroll
      for (int nb = 0; nb < 8; ++nb) {
        const int vrow = nb * 16 + l15;
#pragma unroll
        for (int h = 0; h < 2; ++h) {
          bf16x8 vf = *(const bf16x8*)&lV[vrow * 72 + h * 32 + g * 8];
          acc_o[0][nb] = MFMA16(pa[0][h], vf, acc_o[0][nb]);
          acc_o[1][nb] = MFMA16(pa[1][h], vf, acc_o[1][nb]);
        }
      }
      __builtin_amdgcn_s_setprio(0);
    }

    __syncthreads();
    if (pre) writeV();
    __syncthreads();
    cur ^= 1;
  }

  const int b = bh >> 4, hh = bh & 15;
  float linv[2][4];
#pragma unroll
  for (int mi = 0; mi < 2; ++mi)
#pragma unroll
    for (int r = 0; r < 4; ++r)
      linv[mi][r] = 1.0f / __shfl(lrun[mi], g * 4 + r);
#pragma unroll
  for (int mi = 0; mi < 2; ++mi)
#pragma unroll
    for (int nb = 0; nb < 8; ++nb)
#pragma unroll
      for (int r = 0; r < 4; ++r) {
        const int i = qb * 128 + w * 32 + mi * 16 + g * 4 + r;
        const float o = acc_o[mi][nb][r] * linv[mi][r];
        O[((size_t)(b * 2048 + i)) * 2048 + hh * 128 + nb * 16 + l15] = f2bf(o);
      }
}

// ---------- launch ----------
extern "C" void kernel_launch(void* const* d_in, const int* in_sizes, int n_in,
                              void* d_out, int out_size, void* d_ws, size_t ws_size,
                              hipStream_t stream) {
  const float* x  = (const float*)d_in[0];
  const float* wq = (const float*)d_in[1];
  const float* bq = (const float*)d_in[2];
  const float* wk = (const float*)d_in[3];
  const float* bk = (const float*)d_in[4];
  const float* wv = (const float*)d_in[5];
  const float* bv = (const float*)d_in[6];
  const float* wo = (const float*)d_in[7];
  const float* bo = (const float*)d_in[8];

  const size_t NX = (size_t)2 * 2048 * 2048;
  const size_t NW = (size_t)2048 * 2048;
  const size_t need = (NX + 4 * NW + 3 * NX) * sizeof(unsigned short);  // 96 MB
  if (ws_size < need) return;
  unsigned short* xbf  = (unsigned short*)d_ws;
  unsigned short* wqb  = xbf + NX;
  unsigned short* wkb  = wqb + NW;
  unsigned short* wvb  = wkb + NW;
  unsigned short* wob  = wvb + NW;
  unsigned short* qbuf = wob + NW;
  unsigned short* kbuf = qbuf + NX;
  unsigned short* vbuf = kbuf + NX;
  unsigned short* aobuf = xbf;  // x dead after gemm_qkv (stream-ordered)

  cvt_all<<<dim3(4096, 6), 256, 0, stream>>>(x, wq, wk, wv, wo,
                                             xbf, wqb, wkb, wvb, wob);
  gemm_qkv<<<dim3(16, 16, 3), 512, 0, stream>>>(xbf, wqb, bq, wkb, bk, wvb, bv,
                                                qbuf, kbuf, vbuf);
  attn_fwd<<<dim3(16, 32), 256, 0, stream>>>(qbuf, kbuf, vbuf, aobuf);
  gemm_out<<<dim3(16, 16), 512, 0, stream>>>(aobuf, wob, bo, (float*)d_out);
}